// Round 8
// baseline (2665.781 us; speedup 1.0000x reference)
//
#include <hip/hip_runtime.h>
#include <cstddef>

typedef short short8 __attribute__((ext_vector_type(8)));
typedef _Float16 half8 __attribute__((ext_vector_type(8)));
typedef _Float16 half4 __attribute__((ext_vector_type(4)));
typedef _Float16 half2v __attribute__((ext_vector_type(2)));
typedef float floatx4 __attribute__((ext_vector_type(4)));

// ---- bf16 helpers (round-to-nearest-even) ---------------------------------
__device__ __forceinline__ unsigned short f2bf(float f) {
    unsigned u = __float_as_uint(f);
    u += 0x7FFFu + ((u >> 16) & 1u);
    return (unsigned short)(u >> 16);
}
__device__ __forceinline__ float bf2f(unsigned short h) {
    return __uint_as_float((unsigned)h << 16);
}

// ---------------------------------------------------------------------------
// Fused conv1(3->64,s1,relu) + conv2(64->128,s2,relu):
// conv1 inline fp32 (rolling x-window regs), conv2 split-fp16 MFMA.
// ---------------------------------------------------------------------------
__global__ __launch_bounds__(256)
void fused_conv12_mfma_kernel(const float* __restrict__ x,   // [16,3,256,256]
                              const float* __restrict__ w1,  // [64,3,3,3]
                              const float* __restrict__ b1,
                              const _Float16* __restrict__ w2h, // [9][128][64]
                              const _Float16* __restrict__ w2l,
                              const float* __restrict__ b2,
                              _Float16* __restrict__ outH,   // NHWC [16,128,128,128]
                              _Float16* __restrict__ outL)
{
    __shared__ float s_x[3][11][36];
    __shared__ _Float16 sE[2][9][17][40];   // [plane][row][x/2][ci pad 40]
    __shared__ _Float16 sO[2][9][16][40];

    const int tid = threadIdx.x;
    const int lane = tid & 63;
    const int wave = tid >> 6;
    const int n16 = lane & 15;
    const int quad = lane >> 4;

    const int ox0 = (blockIdx.x & 7) * 16;    // 128/16
    const int oy0 = (blockIdx.x >> 3) * 4;    // 32 y-tiles
    const int co0 = blockIdx.y * 64 + wave * 16;
    const int img = blockIdx.z;

    const int hy0 = oy0 * 2 - 1, hx0 = ox0 * 2 - 1;   // h1 tile origin (9x33)
    const int gy0 = hy0 - 1,     gx0 = hx0 - 1;       // x patch origin (11x35)
    const float* xN = x + (size_t)img * 3 * 65536;

    for (int e = tid; e < 3 * 11 * 35; e += 256) {
        int c = e / 385, r = e % 385;
        int yy = r / 35, xx = r % 35;
        int gy = gy0 + yy, gx = gx0 + xx;
        float v = 0.f;
        if ((unsigned)gy < 256u && (unsigned)gx < 256u)
            v = xN[(size_t)c * 65536 + gy * 256 + gx];
        s_x[c][yy][xx] = v;
    }

    floatx4 acc1[4], acc2[4];
#pragma unroll
    for (int s = 0; s < 4; s++) {
        acc1[s] = (floatx4){0.f, 0.f, 0.f, 0.f};
        acc2[s] = (floatx4){0.f, 0.f, 0.f, 0.f};
    }

    const int pair = tid & 15;
    const int pxg  = tid >> 4;

    for (int c0 = 0; c0 < 64; c0 += 32) {
        __syncthreads();

        const int ch0 = c0 + pair * 2;
        float wA[27], wB[27];
#pragma unroll
        for (int k = 0; k < 27; k++) {
            wA[k] = w1[ch0 * 27 + k];
            wB[k] = w1[ch0 * 27 + 27 + k];
        }
        const float bA = b1[ch0], bB = b1[ch0 + 1];

        for (int px = pxg; px < 33; px += 16) {
            const bool colok = (unsigned)(hx0 + px) < 256u;
            float xw[3][3][3];
#pragma unroll
            for (int c = 0; c < 3; c++)
#pragma unroll
                for (int r = 0; r < 3; r++)
#pragma unroll
                    for (int kx = 0; kx < 3; kx++)
                        xw[c][r][kx] = s_x[c][r][px + kx];
#pragma unroll
            for (int py = 0; py < 9; py++) {
                const bool inb = colok && (unsigned)(hy0 + py) < 256u;
                float aA = bA, aB = bB;
#pragma unroll
                for (int c = 0; c < 3; c++)
#pragma unroll
                    for (int k = 0; k < 9; k++) {
                        const float xv = xw[c][k / 3][k % 3];
                        aA += wA[c * 9 + k] * xv;
                        aB += wB[c * 9 + k] * xv;
                    }
                float vA = inb ? fmaxf(aA, 0.f) : 0.f;
                float vB = inb ? fmaxf(aB, 0.f) : 0.f;
                half2v hv, lv;
                _Float16 hA = (_Float16)vA, hB = (_Float16)vB;
                hv[0] = hA; hv[1] = hB;
                lv[0] = (_Float16)((vA - (float)hA) * 1024.f);
                lv[1] = (_Float16)((vB - (float)hB) * 1024.f);
                _Float16* dH = (px & 1) ? &sO[0][py][px >> 1][pair * 2]
                                        : &sE[0][py][px >> 1][pair * 2];
                _Float16* dL = (px & 1) ? &sO[1][py][px >> 1][pair * 2]
                                        : &sE[1][py][px >> 1][pair * 2];
                *(half2v*)dH = hv;
                *(half2v*)dL = lv;
                if (py < 8) {
#pragma unroll
                    for (int c = 0; c < 3; c++) {
#pragma unroll
                        for (int r = 0; r < 2; r++)
#pragma unroll
                            for (int kx = 0; kx < 3; kx++)
                                xw[c][r][kx] = xw[c][r + 1][kx];
#pragma unroll
                        for (int kx = 0; kx < 3; kx++)
                            xw[c][2][kx] = s_x[c][py + 3][px + kx];
                    }
                }
            }
        }
        __syncthreads();

        half8 ah[9], al[9];
#pragma unroll
        for (int tp = 0; tp < 9; tp++) {
            size_t o = ((size_t)(tp * 128 + co0 + n16)) * 64 + c0 + quad * 8;
            ah[tp] = *(const half8*)(w2h + o);
            al[tp] = *(const half8*)(w2l + o);
        }
#pragma unroll
        for (int oy = 0; oy < 4; oy++) {
#pragma unroll
            for (int tp = 0; tp < 9; tp++) {
                const int kx = tp % 3;
                const int row = oy * 2 + tp / 3;
                half8 bh, bl;
                if (kx == 0)      { bh = *(const half8*)&sE[0][row][n16][quad * 8];
                                    bl = *(const half8*)&sE[1][row][n16][quad * 8]; }
                else if (kx == 1) { bh = *(const half8*)&sO[0][row][n16][quad * 8];
                                    bl = *(const half8*)&sO[1][row][n16][quad * 8]; }
                else              { bh = *(const half8*)&sE[0][row][n16 + 1][quad * 8];
                                    bl = *(const half8*)&sE[1][row][n16 + 1][quad * 8]; }
                acc1[oy] = __builtin_amdgcn_mfma_f32_16x16x32_f16(ah[tp], bh, acc1[oy], 0, 0, 0);
                acc2[oy] = __builtin_amdgcn_mfma_f32_16x16x32_f16(ah[tp], bl, acc2[oy], 0, 0, 0);
                acc2[oy] = __builtin_amdgcn_mfma_f32_16x16x32_f16(al[tp], bh, acc2[oy], 0, 0, 0);
            }
        }
    }

    const float4 bv = *(const float4*)&b2[co0 + quad * 4];
    const float bb[4] = {bv.x, bv.y, bv.z, bv.w};
#pragma unroll
    for (int oy = 0; oy < 4; oy++) {
        half4 hv, lv;
#pragma unroll
        for (int r = 0; r < 4; r++) {
            float v = fmaxf(acc1[oy][r] + acc2[oy][r] * (1.0f / 1024.0f) + bb[r], 0.f);
            _Float16 h = (_Float16)v;
            hv[r] = h;
            lv[r] = (_Float16)((v - (float)h) * 1024.f);
        }
        size_t o = (((size_t)img * 128 + (oy0 + oy)) * 128 + (ox0 + n16)) * 128
                   + co0 + quad * 4;
        *(half4*)(outH + o) = hv;
        *(half4*)(outL + o) = lv;
    }
}

// ---------------------------------------------------------------------------
// Encoder conv weight prepack: OIHW f32 -> [tap][CO][CI] fp16 hi + lo*1024
// ---------------------------------------------------------------------------
template<int CI, int CO>
__global__ __launch_bounds__(256)
void prepack_conv_kernel(const float* __restrict__ w,
                         _Float16* __restrict__ wh, _Float16* __restrict__ wl)
{
    int i = blockIdx.x * 256 + threadIdx.x;
    if (i >= CO * CI * 9) return;
    int co = i / (CI * 9);
    int r  = i % (CI * 9);
    int ci = r / 9;
    int tp = r % 9;
    float v = w[i];
    _Float16 h = (_Float16)v;
    size_t o = ((size_t)tp * CO + co) * CI + ci;
    wh[o] = h;
    wl[o] = (_Float16)((v - (float)h) * 1024.f);
}

// ---------------------------------------------------------------------------
// Split-precision fp16 MFMA 3x3 conv, stride 2, pad 1.  NHWC hi/lo in & out.
// ---------------------------------------------------------------------------
template<int CIN, int COUT, int IH, int IW, bool RELU>
__global__ __launch_bounds__(256)
void conv_mfma_kernel(const _Float16* __restrict__ inH, const _Float16* __restrict__ inL,
                      const _Float16* __restrict__ wpH, const _Float16* __restrict__ wpL,
                      const float* __restrict__ bias,
                      _Float16* __restrict__ outH, _Float16* __restrict__ outL)
{
    constexpr int OH = IH / 2, OW = IW / 2;
    __shared__ _Float16 sE[2][9][17][40];
    __shared__ _Float16 sO[2][9][16][40];

    const int tid = threadIdx.x;
    const int lane = tid & 63;
    const int wave = tid >> 6;
    const int n16 = lane & 15;
    const int quad = lane >> 4;

    constexpr int NTX = OW / 16;
    const int ox0 = (blockIdx.x % NTX) * 16;
    const int oy0 = (blockIdx.x / NTX) * 4;
    const int co0 = blockIdx.y * 64 + wave * 16;
    const int img = blockIdx.z;

    const int iy0 = oy0 * 2 - 1;
    const int ix0 = ox0 * 2 - 1;
    const _Float16* iNH = inH + (size_t)img * IH * IW * CIN;
    const _Float16* iNL = inL + (size_t)img * IH * IW * CIN;

    floatx4 acc1[4], acc2[4];
#pragma unroll
    for (int s = 0; s < 4; s++) {
        acc1[s] = (floatx4){0.f, 0.f, 0.f, 0.f};
        acc2[s] = (floatx4){0.f, 0.f, 0.f, 0.f};
    }

    for (int k0 = 0; k0 < CIN; k0 += 32) {
        __syncthreads();
        for (int e = tid; e < 2376; e += 256) {
            int pl = e / 1188;
            int r  = e % 1188;
            int pix = r >> 2, q = r & 3;
            int py = pix / 33, px = pix % 33;
            int iy = iy0 + py, ix = ix0 + px;
            half8 v = (half8)(_Float16)0;
            if ((unsigned)iy < (unsigned)IH && (unsigned)ix < (unsigned)IW)
                v = *(const half8*)((pl ? iNL : iNH) + ((size_t)(iy * IW + ix) * CIN + k0 + q * 8));
            if (px & 1) *(half8*)&sO[pl][py][px >> 1][q * 8] = v;
            else        *(half8*)&sE[pl][py][px >> 1][q * 8] = v;
        }
        __syncthreads();

        half8 ah[9], al[9];
#pragma unroll
        for (int tp = 0; tp < 9; tp++) {
            size_t o = ((size_t)(tp * COUT + co0 + n16)) * CIN + k0 + quad * 8;
            ah[tp] = *(const half8*)(wpH + o);
            al[tp] = *(const half8*)(wpL + o);
        }

#pragma unroll
        for (int oy = 0; oy < 4; oy++) {
#pragma unroll
            for (int tp = 0; tp < 9; tp++) {
                const int ky = tp / 3, kx = tp % 3;
                const int row = oy * 2 + ky;
                half8 bh, bl;
                if (kx == 0)      { bh = *(const half8*)&sE[0][row][n16][quad * 8];
                                    bl = *(const half8*)&sE[1][row][n16][quad * 8]; }
                else if (kx == 1) { bh = *(const half8*)&sO[0][row][n16][quad * 8];
                                    bl = *(const half8*)&sO[1][row][n16][quad * 8]; }
                else              { bh = *(const half8*)&sE[0][row][n16 + 1][quad * 8];
                                    bl = *(const half8*)&sE[1][row][n16 + 1][quad * 8]; }
                acc1[oy] = __builtin_amdgcn_mfma_f32_16x16x32_f16(ah[tp], bh, acc1[oy], 0, 0, 0);
                acc2[oy] = __builtin_amdgcn_mfma_f32_16x16x32_f16(ah[tp], bl, acc2[oy], 0, 0, 0);
                acc2[oy] = __builtin_amdgcn_mfma_f32_16x16x32_f16(al[tp], bh, acc2[oy], 0, 0, 0);
            }
        }
    }

    const float4 bv = *(const float4*)&bias[co0 + quad * 4];
    const float bb[4] = {bv.x, bv.y, bv.z, bv.w};
#pragma unroll
    for (int oy = 0; oy < 4; oy++) {
        half4 hv, lv;
#pragma unroll
        for (int r = 0; r < 4; r++) {
            float v = acc1[oy][r] + acc2[oy][r] * (1.0f / 1024.0f) + bb[r];
            if (RELU) v = fmaxf(v, 0.f);
            _Float16 h = (_Float16)v;
            hv[r] = h;
            lv[r] = (_Float16)((v - (float)h) * 1024.f);
        }
        size_t o = (((size_t)img * OH + (oy0 + oy)) * OW + (ox0 + n16)) * COUT
                   + co0 + quad * 4;
        *(half4*)(outH + o) = hv;
        *(half4*)(outL + o) = lv;
    }
}

// ---------------------------------------------------------------------------
__global__ __launch_bounds__(64)
void cnorm_kernel(const float* __restrict__ cb, float* __restrict__ cn)
{
    const int code = blockIdx.x;
    const int t = threadIdx.x;
    const float* row = cb + (size_t)code * 512;
    float s = 0.f;
    for (int i = t; i < 512; i += 64) s += row[i] * row[i];
#pragma unroll
    for (int off = 32; off > 0; off >>= 1) s += __shfl_down(s, off, 64);
    if (t == 0) cn[code] = s;
}

__global__ __launch_bounds__(256)
void init_keys_kernel(unsigned long long* __restrict__ keys)
{
    keys[blockIdx.x * 256 + threadIdx.x] = ~0ull;
}

// ---------------------------------------------------------------------------
__global__ __launch_bounds__(256)
void split_cb_kernel(const float* __restrict__ cb,
                     _Float16* __restrict__ ch, _Float16* __restrict__ cl)
{
    size_t i = (size_t)blockIdx.x * 256 + threadIdx.x;
    float v = cb[i];
    _Float16 h = (_Float16)v;
    ch[i] = h;
    cl[i] = (_Float16)((v - (float)h) * 1024.f);
}

// ---------------------------------------------------------------------------
// VQ distance GEMM v3: fp16 split MFMA.
// Grid (x=128 code-blocks, y=64 row-blocks) -> z rows L2-resident, cb streams.
// Block 256 = 4 waves; block tile 256 rows x 64 codes; wave = 64 rows x 64.
// B staged fragment-ordered in LDS (lane-linear ds_read_b128, conflict-free),
// double-buffered; 48 MFMA per 8 LDS reads per chunk.
// ---------------------------------------------------------------------------
__global__ __launch_bounds__(256)
void vq_mfma_kernel(const _Float16* __restrict__ zh, const _Float16* __restrict__ zl,
                    const _Float16* __restrict__ ch, const _Float16* __restrict__ cl,
                    const float* __restrict__ cn,
                    unsigned long long* __restrict__ keys)   // [16384]
{
    __shared__ _Float16 sB[2][512 * 8];   // [buf][frag e][8], e=((pl*4+ct)*16+n16)*4+quad

    const int tid = threadIdx.x;
    const int lane = tid & 63;
    const int wave = tid >> 6;
    const int n16 = lane & 15;
    const int quad = lane >> 4;

    const int code0 = blockIdx.x * 64;
    const int row0 = blockIdx.y * 256 + wave * 64;

    floatx4 acc1[4][4], acc2[4][4];
#pragma unroll
    for (int rt = 0; rt < 4; rt++)
#pragma unroll
        for (int ct = 0; ct < 4; ct++) {
            acc1[rt][ct] = (floatx4){0.f, 0.f, 0.f, 0.f};
            acc2[rt][ct] = (floatx4){0.f, 0.f, 0.f, 0.f};
        }

    const _Float16* pzh = zh + (size_t)(row0 + n16) * 512 + quad * 8;
    const _Float16* pzl = zl + (size_t)(row0 + n16) * 512 + quad * 8;

    // staging: thread handles frags e0=tid, e1=tid+256; dst = sB[buf]+e*8
    const int e0 = tid, e1 = tid + 256;
    const _Float16* s0 = ((e0 >> 8) ? cl : ch)
        + (size_t)(code0 + ((e0 >> 6) & 3) * 16 + ((e0 >> 2) & 15)) * 512 + (e0 & 3) * 8;
    const _Float16* s1 = ((e1 >> 8) ? cl : ch)
        + (size_t)(code0 + ((e1 >> 6) & 3) * 16 + ((e1 >> 2) & 15)) * 512 + (e1 & 3) * 8;

    *(half8*)&sB[0][e0 * 8] = *(const half8*)s0;
    *(half8*)&sB[0][e1 * 8] = *(const half8*)s1;
    __syncthreads();

    for (int c = 0; c < 16; ++c) {
        const int cur = c & 1;
        const int kk = c * 32;
        half8 ah[4], al[4];
#pragma unroll
        for (int rt = 0; rt < 4; rt++) {
            ah[rt] = *(const half8*)(pzh + (size_t)rt * 8192 + kk);
            al[rt] = *(const half8*)(pzl + (size_t)rt * 8192 + kk);
        }
        half8 t0, t1;
        if (c < 15) {
            t0 = *(const half8*)(s0 + kk + 32);
            t1 = *(const half8*)(s1 + kk + 32);
        }
#pragma unroll
        for (int ct = 0; ct < 4; ++ct) {
            half8 bh = *(const half8*)&sB[cur][(ct * 64 + n16 * 4 + quad) * 8];
            half8 bl = *(const half8*)&sB[cur][(256 + ct * 64 + n16 * 4 + quad) * 8];
#pragma unroll
            for (int rt = 0; rt < 4; rt++) {
                acc1[rt][ct] = __builtin_amdgcn_mfma_f32_16x16x32_f16(ah[rt], bh, acc1[rt][ct], 0, 0, 0);
                acc2[rt][ct] = __builtin_amdgcn_mfma_f32_16x16x32_f16(ah[rt], bl, acc2[rt][ct], 0, 0, 0);
                acc2[rt][ct] = __builtin_amdgcn_mfma_f32_16x16x32_f16(al[rt], bh, acc2[rt][ct], 0, 0, 0);
            }
        }
        if (c < 15) {
            const int nxt = cur ^ 1;
            *(half8*)&sB[nxt][e0 * 8] = t0;
            *(half8*)&sB[nxt][e1 * 8] = t1;
        }
        __syncthreads();
    }

#pragma unroll
    for (int rt = 0; rt < 4; rt++) {
#pragma unroll
        for (int reg = 0; reg < 4; reg++) {
            float best = 3.0e38f;
            int bcode = 0;
#pragma unroll
            for (int ct = 0; ct < 4; ct++) {
                const int code = code0 + ct * 16 + n16;
                float dot = acc1[rt][ct][reg] + acc2[rt][ct][reg] * (1.0f / 1024.0f);
                float s = cn[code] - 2.0f * dot;
                if (s < best) { best = s; bcode = code; }
            }
            unsigned u = __float_as_uint(best);
            u = (u & 0x80000000u) ? ~u : (u | 0x80000000u);
            unsigned long long key = ((unsigned long long)u << 32) | (unsigned)bcode;
#pragma unroll
            for (int m = 1; m < 16; m <<= 1) {
                unsigned long long o = __shfl_xor(key, m, 64);
                key = (o < key) ? o : key;
            }
            if (n16 == 0)
                atomicMin(&keys[row0 + rt * 16 + quad * 4 + reg], key);
        }
    }
}

// ---------------------------------------------------------------------------
// Gather: indices (float) into d_out tail, zq as bf16 NHWC [16,32,32,512].
// ---------------------------------------------------------------------------
__global__ __launch_bounds__(256)
void vq_gather_kernel(const unsigned long long* __restrict__ keys,
                      const float* __restrict__ cb,
                      unsigned short* __restrict__ zq, float* __restrict__ idx_out)
{
    __shared__ int sidx[64];
    const int t = threadIdx.x;
    const int v0 = blockIdx.x * 64;
    if (t < 64) {
        int idx = (int)(keys[v0 + t] & 0xFFFFFFFFull);
        sidx[t] = idx;
        idx_out[v0 + t] = (float)idx;
    }
    __syncthreads();
    const int tv = t >> 2;
    const int q = t & 3;
    const float* crow = cb + (size_t)sidx[tv] * 512;
    unsigned short* zrow = zq + (size_t)(v0 + tv) * 512;
    for (int c = q * 8; c < 512; c += 32) {
        float4 f0 = *(const float4*)(crow + c);
        float4 f1 = *(const float4*)(crow + c + 4);
        short8 h;
        h[0] = (short)f2bf(f0.x); h[1] = (short)f2bf(f0.y);
        h[2] = (short)f2bf(f0.z); h[3] = (short)f2bf(f0.w);
        h[4] = (short)f2bf(f1.x); h[5] = (short)f2bf(f1.y);
        h[6] = (short)f2bf(f1.z); h[7] = (short)f2bf(f1.w);
        *(short8*)(zrow + c) = h;
    }
}

// ---------------------------------------------------------------------------
// Deconv weight prepack: torch [CI][CO][3][3] f32 -> [tap][CO][CI] bf16
// ---------------------------------------------------------------------------
template<int CI, int CO>
__global__ __launch_bounds__(256)
void prepack_kernel(const float* __restrict__ w, unsigned short* __restrict__ wp)
{
    int i = blockIdx.x * 256 + threadIdx.x;
    if (i >= 9 * CO * CI) return;
    int ci = i / (CO * 9);
    int r  = i % (CO * 9);
    int co = r / 9;
    int tp = r % 9;
    wp[((size_t)tp * CO + co) * CI + ci] = f2bf(w[i]);
}

// ---------------------------------------------------------------------------
// MFMA ConvTranspose2d k=3 s=2 p=1 op=1 + ReLU, bf16.
// ---------------------------------------------------------------------------
template<int CIN, int COUT, int IH, int IW, bool OUT_NCHW>
__global__ __launch_bounds__(256)
void deconv_mfma_kernel(const unsigned short* __restrict__ in,   // NHWC bf16
                        const unsigned short* __restrict__ wp,   // [9][CO][CI] bf16
                        const float* __restrict__ bias,
                        unsigned short* __restrict__ out)        // bf16
{
    constexpr int OH = 2 * IH, OW = 2 * IW;
    __shared__ short sIn[5][17][40];

    const int tid = threadIdx.x;
    const int lane = tid & 63;
    const int wave = tid >> 6;
    const int n16 = lane & 15;
    const int quad = lane >> 4;

    constexpr int NTX = IW / 16;
    const int x0 = (blockIdx.x % NTX) * 16;
    const int y0 = (blockIdx.x / NTX) * 4;
    const int co0 = blockIdx.y * 64 + wave * 16;
    const int img = blockIdx.z;

    const unsigned short* inN = in + (size_t)img * IH * IW * CIN;

    floatx4 acc[4][4];
#pragma unroll
    for (int s = 0; s < 4; s++)
#pragma unroll
        for (int c = 0; c < 4; c++) acc[s][c] = (floatx4){0.f, 0.f, 0.f, 0.f};

    for (int k0 = 0; k0 < CIN; k0 += 32) {
        __syncthreads();
        for (int e = tid; e < 340; e += 256) {
            int yy = e / 68, r = e % 68;
            int xx = r >> 2, q4 = r & 3;
            int gy = y0 + yy, gx = x0 + xx;
            short8 v = {0, 0, 0, 0, 0, 0, 0, 0};
            if (gy < IH && gx < IW)
                v = *(const short8*)(inN + ((size_t)(gy * IW + gx) * CIN + k0 + q4 * 8));
            *(short8*)&sIn[yy][xx][q4 * 8] = v;
        }
        __syncthreads();

        short8 a[9];
#pragma unroll
        for (int tp = 0; tp < 9; tp++)
            a[tp] = *(const short8*)(wp + ((size_t)(tp * COUT + co0 + n16) * CIN + k0 + quad * 8));

#pragma unroll
        for (int s = 0; s < 4; s++) {
            short8 b00 = *(const short8*)&sIn[s    ][n16    ][quad * 8];
            short8 b01 = *(const short8*)&sIn[s    ][n16 + 1][quad * 8];
            short8 b10 = *(const short8*)&sIn[s + 1][n16    ][quad * 8];
            short8 b11 = *(const short8*)&sIn[s + 1][n16 + 1][quad * 8];
            acc[s][0] = __builtin_amdgcn_mfma_f32_16x16x32_bf16(a[4], b00, acc[s][0], 0, 0, 0);
            acc[s][1] = __builtin_amdgcn_mfma_f32_16x16x32_bf16(a[3], b01, acc[s][1], 0, 0, 0);
            acc[s][1] = __builtin_amdgcn_mfma_f32_16x16x32_bf16(a[5], b00, acc[s][1], 0, 0, 0);
            acc[s][2] = __builtin_amdgcn_mfma_f32_16x16x32_bf16(a[1], b10, acc[s][2], 0, 0, 0);
            acc[s][2] = __builtin_amdgcn_mfma_f32_16x16x32_bf16(a[7], b00, acc[s][2], 0, 0, 0);
            acc[s][3] = __builtin_amdgcn_mfma_f32_16x16x32_bf16(a[0], b11, acc[s][3], 0, 0, 0);
            acc[s][3] = __builtin_amdgcn_mfma_f32_16x16x32_bf16(a[2], b10, acc[s][3], 0, 0, 0);
            acc[s][3] = __builtin_amdgcn_mfma_f32_16x16x32_bf16(a[6], b01, acc[s][3], 0, 0, 0);
            acc[s][3] = __builtin_amdgcn_mfma_f32_16x16x32_bf16(a[8], b00, acc[s][3], 0, 0, 0);
        }
    }

    const float4 bv = *(const float4*)&bias[co0 + quad * 4];
    const float bb[4] = {bv.x, bv.y, bv.z, bv.w};
    const int x = x0 + n16;

    if (!OUT_NCHW) {
        unsigned short* outN = out + (size_t)img * OH * OW * COUT;
#pragma unroll
        for (int s = 0; s < 4; s++) {
            const int y = y0 + s;
#pragma unroll
            for (int c = 0; c < 4; c++) {
                const int oy = 2 * y + (c >> 1);
                const int ox = 2 * x + (c & 1);
                ushort4 h;
                h.x = f2bf(fmaxf(acc[s][c][0] + bb[0], 0.f));
                h.y = f2bf(fmaxf(acc[s][c][1] + bb[1], 0.f));
                h.z = f2bf(fmaxf(acc[s][c][2] + bb[2], 0.f));
                h.w = f2bf(fmaxf(acc[s][c][3] + bb[3], 0.f));
                *(ushort4*)(outN + ((size_t)(oy * OW + ox) * COUT + co0 + quad * 4)) = h;
            }
        }
    } else {
#pragma unroll
        for (int s = 0; s < 4; s++) {
            const int y = y0 + s;
#pragma unroll
            for (int r = 0; r < 4; r++) {
                const int co = co0 + quad * 4 + r;
                unsigned short* oC = out + (size_t)(img * COUT + co) * OH * OW;
                unsigned p0 = (unsigned)f2bf(fmaxf(acc[s][0][r] + bb[r], 0.f)) |
                              ((unsigned)f2bf(fmaxf(acc[s][1][r] + bb[r], 0.f)) << 16);
                unsigned p1 = (unsigned)f2bf(fmaxf(acc[s][2][r] + bb[r], 0.f)) |
                              ((unsigned)f2bf(fmaxf(acc[s][3][r] + bb[r], 0.f)) << 16);
                *(unsigned*)(oC + (size_t)(2 * y) * OW + 2 * x) = p0;
                *(unsigned*)(oC + (size_t)(2 * y + 1) * OW + 2 * x) = p1;
            }
        }
    }
}

// ---------------------------------------------------------------------------
// Final conv 64->3 + sigmoid. NCHW bf16 input, fp32 out (d_out).
// ---------------------------------------------------------------------------
__global__ __launch_bounds__(256)
void conv_out_kernel(const unsigned short* __restrict__ in, // [16,64,256,256] bf16
                     const float* __restrict__ w,           // [3,64,3,3]
                     const float* __restrict__ bias,
                     float* __restrict__ out)               // [16,3,256,256]
{
    constexpr int TIC = 4;
    __shared__ float s_in[TIC][3][258];
    const int t = threadIdx.x;
    const int y = blockIdx.x;
    const int n = blockIdx.y;
    const unsigned short* inN = in + (size_t)n * 64 * 65536;
    float acc0 = bias[0], acc1 = bias[1], acc2 = bias[2];

    for (int c0 = 0; c0 < 64; c0 += TIC) {
        for (int e = t; e < TIC * 3 * 258; e += 256) {
            int ci = e / 774;
            int r  = e % 774;
            int ry = r / 258, xx = r % 258;
            int gy = y - 1 + ry, gx = xx - 1;
            float v = 0.f;
            if ((unsigned)gy < 256u && (unsigned)gx < 256u)
                v = bf2f(inN[(size_t)(c0 + ci) * 65536 + gy * 256 + gx]);
            s_in[ci][ry][xx] = v;
        }
        __syncthreads();
#pragma unroll
        for (int ci = 0; ci < TIC; ++ci) {
            float iv[3][3];
#pragma unroll
            for (int ry = 0; ry < 3; ry++)
#pragma unroll
                for (int kx = 0; kx < 3; kx++)
                    iv[ry][kx] = s_in[ci][ry][t + kx];
#pragma unroll
            for (int k = 0; k < 9; k++) {
                const float v = iv[k / 3][k % 3];
                acc0 += w[(0 * 64 + c0 + ci) * 9 + k] * v;
                acc1 += w[(1 * 64 + c0 + ci) * 9 + k] * v;
                acc2 += w[(2 * 64 + c0 + ci) * 9 + k] * v;
            }
        }
        __syncthreads();
    }
    const size_t o = (size_t)((n * 3 + 0) * 256 + y) * 256 + t;
    out[o]          = 1.f / (1.f + __expf(-acc0));
    out[o + 65536]  = 1.f / (1.f + __expf(-acc1));
    out[o + 131072] = 1.f / (1.f + __expf(-acc2));
}

// ---------------------------------------------------------------------------
// Workspace (peak 201.5 MB) — same layout as rounds 6/7.
// ---------------------------------------------------------------------------
extern "C" void kernel_launch(void* const* d_in, const int* in_sizes, int n_in,
                              void* d_out, int out_size, void* d_ws, size_t ws_size,
                              hipStream_t stream)
{
    const float* x   = (const float*)d_in[0];
    const float* w1  = (const float*)d_in[1];
    const float* b1  = (const float*)d_in[2];
    const float* w2  = (const float*)d_in[3];
    const float* b2  = (const float*)d_in[4];
    const float* w3  = (const float*)d_in[5];
    const float* b3  = (const float*)d_in[6];
    const float* w4  = (const float*)d_in[7];
    const float* b4  = (const float*)d_in[8];
    const float* cb  = (const float*)d_in[9];
    const float* d1w = (const float*)d_in[10];
    const float* d1b = (const float*)d_in[11];
    const float* d2w = (const float*)d_in[12];
    const float* d2b = (const float*)d_in[13];
    const float* d3w = (const float*)d_in[14];
    const float* d3b = (const float*)d_in[15];
    const float* wo  = (const float*)d_in[16];
    const float* bo  = (const float*)d_in[17];

    char* ws = (char*)d_ws;
    _Float16* H2H = (_Float16*)(ws);
    _Float16* H2L = (_Float16*)(ws + 67108864);
    _Float16* H3H = (_Float16*)(ws + 134217728);
    _Float16* H3L = (_Float16*)(ws + 167772160);
    _Float16* ZH  = (_Float16*)(ws);
    _Float16* ZL  = (_Float16*)(ws + 16777216);
    unsigned short* ZQ = (unsigned short*)(ws + 33554432);
    _Float16* CBH = (_Float16*)(ws + 50331648);
    _Float16* CBL = (_Float16*)(ws + 58720256);
    unsigned short* G1 = (unsigned short*)(ws + 67108864);
    unsigned short* G2 = (unsigned short*)(ws + 134217728);
    unsigned short* G3 = (unsigned short*)(ws);
    unsigned long long* keys = (unsigned long long*)(ws + 201326592);
    float* cn = (float*)(ws + 201326592 + 131072);

    char* oscratch = (char*)d_out;
    _Float16* EW3H = (_Float16*)(oscratch);
    _Float16* EW3L = (_Float16*)(oscratch + 589824);
    _Float16* EW4H = (_Float16*)(oscratch + 1179648);
    _Float16* EW4L = (_Float16*)(oscratch + 3538944);
    unsigned short* WP1 = (unsigned short*)(oscratch + 5898240);
    unsigned short* WP2 = (unsigned short*)(oscratch + 8257536);
    unsigned short* WP3 = (unsigned short*)(oscratch + 8847360);
    _Float16* EW2H = (_Float16*)(oscratch + 8994816);
    _Float16* EW2L = (_Float16*)(oscratch + 9142272);

    float* xrec = (float*)d_out;
    float* idxf = (float*)d_out + (size_t)16 * 3 * 256 * 256;

    // ---- weight prepacks ----
    prepack_conv_kernel<64,  128><<<288,  256, 0, stream>>>(w2, EW2H, EW2L);
    prepack_conv_kernel<128, 256><<<1152, 256, 0, stream>>>(w3, EW3H, EW3L);
    prepack_conv_kernel<256, 512><<<4608, 256, 0, stream>>>(w4, EW4H, EW4L);
    prepack_kernel<512, 256><<<4608, 256, 0, stream>>>(d1w, WP1);
    prepack_kernel<256, 128><<<1152, 256, 0, stream>>>(d2w, WP2);
    prepack_kernel<128, 64 ><<<288,  256, 0, stream>>>(d3w, WP3);

    // ---- encoder ----
    fused_conv12_mfma_kernel<<<dim3(256, 2, 16), 256, 0, stream>>>(x, w1, b1, EW2H, EW2L, b2, H2H, H2L);
    conv_mfma_kernel<128, 256, 128, 128, true ><<<dim3(64, 4, 16), 256, 0, stream>>>(H2H, H2L, EW3H, EW3L, b3, H3H, H3L);
    conv_mfma_kernel<256, 512, 64,  64,  false><<<dim3(16, 8, 16), 256, 0, stream>>>(H3H, H3L, EW4H, EW4L, b4, ZH, ZL);

    // ---- VQ ----
    cnorm_kernel<<<8192, 64, 0, stream>>>(cb, cn);
    init_keys_kernel<<<64, 256, 0, stream>>>(keys);
    split_cb_kernel<<<16384, 256, 0, stream>>>(cb, CBH, CBL);
    vq_mfma_kernel<<<dim3(128, 64), 256, 0, stream>>>(ZH, ZL, CBH, CBL, cn, keys);
    vq_gather_kernel<<<256, 256, 0, stream>>>(keys, cb, ZQ, idxf);

    // ---- decoder (bf16 MFMA) ----
    deconv_mfma_kernel<512, 256, 32,  32,  false><<<dim3(16,  4, 16), 256, 0, stream>>>(ZQ, WP1, d1b, G1);
    deconv_mfma_kernel<256, 128, 64,  64,  false><<<dim3(64,  2, 16), 256, 0, stream>>>(G1, WP2, d2b, G2);
    deconv_mfma_kernel<128, 64,  128, 128, true ><<<dim3(256, 1, 16), 256, 0, stream>>>(G2, WP3, d3b, G3);
    conv_out_kernel<<<dim3(256, 16), 256, 0, stream>>>(G3, wo, bo, xrec);
}

// Round 9
// 2583.903 us; speedup vs baseline: 1.0317x; 1.0317x over previous
//
#include <hip/hip_runtime.h>
#include <cstddef>

typedef short short8 __attribute__((ext_vector_type(8)));
typedef _Float16 half8 __attribute__((ext_vector_type(8)));
typedef _Float16 half4 __attribute__((ext_vector_type(4)));
typedef _Float16 half2v __attribute__((ext_vector_type(2)));
typedef float floatx4 __attribute__((ext_vector_type(4)));

// ---- bf16 helpers (round-to-nearest-even) ---------------------------------
__device__ __forceinline__ unsigned short f2bf(float f) {
    unsigned u = __float_as_uint(f);
    u += 0x7FFFu + ((u >> 16) & 1u);
    return (unsigned short)(u >> 16);
}
__device__ __forceinline__ float bf2f(unsigned short h) {
    return __uint_as_float((unsigned)h << 16);
}

// ---------------------------------------------------------------------------
// Fused conv1(3->64,s1,relu) + conv2(64->128,s2,relu):
// conv1 inline fp32 (rolling x-window regs), conv2 split-fp16 MFMA.
// ---------------------------------------------------------------------------
__global__ __launch_bounds__(256)
void fused_conv12_mfma_kernel(const float* __restrict__ x,   // [16,3,256,256]
                              const float* __restrict__ w1,  // [64,3,3,3]
                              const float* __restrict__ b1,
                              const _Float16* __restrict__ w2h, // [9][128][64]
                              const _Float16* __restrict__ w2l,
                              const float* __restrict__ b2,
                              _Float16* __restrict__ outH,   // NHWC [16,128,128,128]
                              _Float16* __restrict__ outL)
{
    __shared__ float s_x[3][11][36];
    __shared__ _Float16 sE[2][9][17][40];   // [plane][row][x/2][ci pad 40]
    __shared__ _Float16 sO[2][9][16][40];

    const int tid = threadIdx.x;
    const int lane = tid & 63;
    const int wave = tid >> 6;
    const int n16 = lane & 15;
    const int quad = lane >> 4;

    const int ox0 = (blockIdx.x & 7) * 16;    // 128/16
    const int oy0 = (blockIdx.x >> 3) * 4;    // 32 y-tiles
    const int co0 = blockIdx.y * 64 + wave * 16;
    const int img = blockIdx.z;

    const int hy0 = oy0 * 2 - 1, hx0 = ox0 * 2 - 1;   // h1 tile origin (9x33)
    const int gy0 = hy0 - 1,     gx0 = hx0 - 1;       // x patch origin (11x35)
    const float* xN = x + (size_t)img * 3 * 65536;

    for (int e = tid; e < 3 * 11 * 35; e += 256) {
        int c = e / 385, r = e % 385;
        int yy = r / 35, xx = r % 35;
        int gy = gy0 + yy, gx = gx0 + xx;
        float v = 0.f;
        if ((unsigned)gy < 256u && (unsigned)gx < 256u)
            v = xN[(size_t)c * 65536 + gy * 256 + gx];
        s_x[c][yy][xx] = v;
    }

    floatx4 acc1[4], acc2[4];
#pragma unroll
    for (int s = 0; s < 4; s++) {
        acc1[s] = (floatx4){0.f, 0.f, 0.f, 0.f};
        acc2[s] = (floatx4){0.f, 0.f, 0.f, 0.f};
    }

    const int pair = tid & 15;
    const int pxg  = tid >> 4;

    for (int c0 = 0; c0 < 64; c0 += 32) {
        __syncthreads();

        const int ch0 = c0 + pair * 2;
        float wA[27], wB[27];
#pragma unroll
        for (int k = 0; k < 27; k++) {
            wA[k] = w1[ch0 * 27 + k];
            wB[k] = w1[ch0 * 27 + 27 + k];
        }
        const float bA = b1[ch0], bB = b1[ch0 + 1];

        for (int px = pxg; px < 33; px += 16) {
            const bool colok = (unsigned)(hx0 + px) < 256u;
            float xw[3][3][3];
#pragma unroll
            for (int c = 0; c < 3; c++)
#pragma unroll
                for (int r = 0; r < 3; r++)
#pragma unroll
                    for (int kx = 0; kx < 3; kx++)
                        xw[c][r][kx] = s_x[c][r][px + kx];
#pragma unroll
            for (int py = 0; py < 9; py++) {
                const bool inb = colok && (unsigned)(hy0 + py) < 256u;
                float aA = bA, aB = bB;
#pragma unroll
                for (int c = 0; c < 3; c++)
#pragma unroll
                    for (int k = 0; k < 9; k++) {
                        const float xv = xw[c][k / 3][k % 3];
                        aA += wA[c * 9 + k] * xv;
                        aB += wB[c * 9 + k] * xv;
                    }
                float vA = inb ? fmaxf(aA, 0.f) : 0.f;
                float vB = inb ? fmaxf(aB, 0.f) : 0.f;
                half2v hv, lv;
                _Float16 hA = (_Float16)vA, hB = (_Float16)vB;
                hv[0] = hA; hv[1] = hB;
                lv[0] = (_Float16)((vA - (float)hA) * 1024.f);
                lv[1] = (_Float16)((vB - (float)hB) * 1024.f);
                _Float16* dH = (px & 1) ? &sO[0][py][px >> 1][pair * 2]
                                        : &sE[0][py][px >> 1][pair * 2];
                _Float16* dL = (px & 1) ? &sO[1][py][px >> 1][pair * 2]
                                        : &sE[1][py][px >> 1][pair * 2];
                *(half2v*)dH = hv;
                *(half2v*)dL = lv;
                if (py < 8) {
#pragma unroll
                    for (int c = 0; c < 3; c++) {
#pragma unroll
                        for (int r = 0; r < 2; r++)
#pragma unroll
                            for (int kx = 0; kx < 3; kx++)
                                xw[c][r][kx] = xw[c][r + 1][kx];
#pragma unroll
                        for (int kx = 0; kx < 3; kx++)
                            xw[c][2][kx] = s_x[c][py + 3][px + kx];
                    }
                }
            }
        }
        __syncthreads();

        half8 ah[9], al[9];
#pragma unroll
        for (int tp = 0; tp < 9; tp++) {
            size_t o = ((size_t)(tp * 128 + co0 + n16)) * 64 + c0 + quad * 8;
            ah[tp] = *(const half8*)(w2h + o);
            al[tp] = *(const half8*)(w2l + o);
        }
#pragma unroll
        for (int oy = 0; oy < 4; oy++) {
#pragma unroll
            for (int tp = 0; tp < 9; tp++) {
                const int kx = tp % 3;
                const int row = oy * 2 + tp / 3;
                half8 bh, bl;
                if (kx == 0)      { bh = *(const half8*)&sE[0][row][n16][quad * 8];
                                    bl = *(const half8*)&sE[1][row][n16][quad * 8]; }
                else if (kx == 1) { bh = *(const half8*)&sO[0][row][n16][quad * 8];
                                    bl = *(const half8*)&sO[1][row][n16][quad * 8]; }
                else              { bh = *(const half8*)&sE[0][row][n16 + 1][quad * 8];
                                    bl = *(const half8*)&sE[1][row][n16 + 1][quad * 8]; }
                acc1[oy] = __builtin_amdgcn_mfma_f32_16x16x32_f16(ah[tp], bh, acc1[oy], 0, 0, 0);
                acc2[oy] = __builtin_amdgcn_mfma_f32_16x16x32_f16(ah[tp], bl, acc2[oy], 0, 0, 0);
                acc2[oy] = __builtin_amdgcn_mfma_f32_16x16x32_f16(al[tp], bh, acc2[oy], 0, 0, 0);
            }
        }
    }

    const float4 bv = *(const float4*)&b2[co0 + quad * 4];
    const float bb[4] = {bv.x, bv.y, bv.z, bv.w};
#pragma unroll
    for (int oy = 0; oy < 4; oy++) {
        half4 hv, lv;
#pragma unroll
        for (int r = 0; r < 4; r++) {
            float v = fmaxf(acc1[oy][r] + acc2[oy][r] * (1.0f / 1024.0f) + bb[r], 0.f);
            _Float16 h = (_Float16)v;
            hv[r] = h;
            lv[r] = (_Float16)((v - (float)h) * 1024.f);
        }
        size_t o = (((size_t)img * 128 + (oy0 + oy)) * 128 + (ox0 + n16)) * 128
                   + co0 + quad * 4;
        *(half4*)(outH + o) = hv;
        *(half4*)(outL + o) = lv;
    }
}

// ---------------------------------------------------------------------------
// Encoder conv weight prepack: OIHW f32 -> [tap][CO][CI] fp16 hi + lo*1024
// ---------------------------------------------------------------------------
template<int CI, int CO>
__global__ __launch_bounds__(256)
void prepack_conv_kernel(const float* __restrict__ w,
                         _Float16* __restrict__ wh, _Float16* __restrict__ wl)
{
    int i = blockIdx.x * 256 + threadIdx.x;
    if (i >= CO * CI * 9) return;
    int co = i / (CI * 9);
    int r  = i % (CI * 9);
    int ci = r / 9;
    int tp = r % 9;
    float v = w[i];
    _Float16 h = (_Float16)v;
    size_t o = ((size_t)tp * CO + co) * CI + ci;
    wh[o] = h;
    wl[o] = (_Float16)((v - (float)h) * 1024.f);
}

// ---------------------------------------------------------------------------
// Split-precision fp16 MFMA 3x3 conv, stride 2, pad 1.  NHWC hi/lo in & out.
// ---------------------------------------------------------------------------
template<int CIN, int COUT, int IH, int IW, bool RELU>
__global__ __launch_bounds__(256)
void conv_mfma_kernel(const _Float16* __restrict__ inH, const _Float16* __restrict__ inL,
                      const _Float16* __restrict__ wpH, const _Float16* __restrict__ wpL,
                      const float* __restrict__ bias,
                      _Float16* __restrict__ outH, _Float16* __restrict__ outL)
{
    constexpr int OH = IH / 2, OW = IW / 2;
    __shared__ _Float16 sE[2][9][17][40];
    __shared__ _Float16 sO[2][9][16][40];

    const int tid = threadIdx.x;
    const int lane = tid & 63;
    const int wave = tid >> 6;
    const int n16 = lane & 15;
    const int quad = lane >> 4;

    constexpr int NTX = OW / 16;
    const int ox0 = (blockIdx.x % NTX) * 16;
    const int oy0 = (blockIdx.x / NTX) * 4;
    const int co0 = blockIdx.y * 64 + wave * 16;
    const int img = blockIdx.z;

    const int iy0 = oy0 * 2 - 1;
    const int ix0 = ox0 * 2 - 1;
    const _Float16* iNH = inH + (size_t)img * IH * IW * CIN;
    const _Float16* iNL = inL + (size_t)img * IH * IW * CIN;

    floatx4 acc1[4], acc2[4];
#pragma unroll
    for (int s = 0; s < 4; s++) {
        acc1[s] = (floatx4){0.f, 0.f, 0.f, 0.f};
        acc2[s] = (floatx4){0.f, 0.f, 0.f, 0.f};
    }

    for (int k0 = 0; k0 < CIN; k0 += 32) {
        __syncthreads();
        for (int e = tid; e < 2376; e += 256) {
            int pl = e / 1188;
            int r  = e % 1188;
            int pix = r >> 2, q = r & 3;
            int py = pix / 33, px = pix % 33;
            int iy = iy0 + py, ix = ix0 + px;
            half8 v = (half8)(_Float16)0;
            if ((unsigned)iy < (unsigned)IH && (unsigned)ix < (unsigned)IW)
                v = *(const half8*)((pl ? iNL : iNH) + ((size_t)(iy * IW + ix) * CIN + k0 + q * 8));
            if (px & 1) *(half8*)&sO[pl][py][px >> 1][q * 8] = v;
            else        *(half8*)&sE[pl][py][px >> 1][q * 8] = v;
        }
        __syncthreads();

        half8 ah[9], al[9];
#pragma unroll
        for (int tp = 0; tp < 9; tp++) {
            size_t o = ((size_t)(tp * COUT + co0 + n16)) * CIN + k0 + quad * 8;
            ah[tp] = *(const half8*)(wpH + o);
            al[tp] = *(const half8*)(wpL + o);
        }

#pragma unroll
        for (int oy = 0; oy < 4; oy++) {
#pragma unroll
            for (int tp = 0; tp < 9; tp++) {
                const int ky = tp / 3, kx = tp % 3;
                const int row = oy * 2 + ky;
                half8 bh, bl;
                if (kx == 0)      { bh = *(const half8*)&sE[0][row][n16][quad * 8];
                                    bl = *(const half8*)&sE[1][row][n16][quad * 8]; }
                else if (kx == 1) { bh = *(const half8*)&sO[0][row][n16][quad * 8];
                                    bl = *(const half8*)&sO[1][row][n16][quad * 8]; }
                else              { bh = *(const half8*)&sE[0][row][n16 + 1][quad * 8];
                                    bl = *(const half8*)&sE[1][row][n16 + 1][quad * 8]; }
                acc1[oy] = __builtin_amdgcn_mfma_f32_16x16x32_f16(ah[tp], bh, acc1[oy], 0, 0, 0);
                acc2[oy] = __builtin_amdgcn_mfma_f32_16x16x32_f16(ah[tp], bl, acc2[oy], 0, 0, 0);
                acc2[oy] = __builtin_amdgcn_mfma_f32_16x16x32_f16(al[tp], bh, acc2[oy], 0, 0, 0);
            }
        }
    }

    const float4 bv = *(const float4*)&bias[co0 + quad * 4];
    const float bb[4] = {bv.x, bv.y, bv.z, bv.w};
#pragma unroll
    for (int oy = 0; oy < 4; oy++) {
        half4 hv, lv;
#pragma unroll
        for (int r = 0; r < 4; r++) {
            float v = acc1[oy][r] + acc2[oy][r] * (1.0f / 1024.0f) + bb[r];
            if (RELU) v = fmaxf(v, 0.f);
            _Float16 h = (_Float16)v;
            hv[r] = h;
            lv[r] = (_Float16)((v - (float)h) * 1024.f);
        }
        size_t o = (((size_t)img * OH + (oy0 + oy)) * OW + (ox0 + n16)) * COUT
                   + co0 + quad * 4;
        *(half4*)(outH + o) = hv;
        *(half4*)(outL + o) = lv;
    }
}

// ---------------------------------------------------------------------------
__global__ __launch_bounds__(64)
void cnorm_kernel(const float* __restrict__ cb, float* __restrict__ cn)
{
    const int code = blockIdx.x;
    const int t = threadIdx.x;
    const float* row = cb + (size_t)code * 512;
    float s = 0.f;
    for (int i = t; i < 512; i += 64) s += row[i] * row[i];
#pragma unroll
    for (int off = 32; off > 0; off >>= 1) s += __shfl_down(s, off, 64);
    if (t == 0) cn[code] = s;
}

__global__ __launch_bounds__(256)
void init_keys_kernel(unsigned long long* __restrict__ keys)
{
    keys[blockIdx.x * 256 + threadIdx.x] = ~0ull;
}

// ---------------------------------------------------------------------------
__global__ __launch_bounds__(256)
void split_cb_kernel(const float* __restrict__ cb,
                     _Float16* __restrict__ ch, _Float16* __restrict__ cl)
{
    size_t i = (size_t)blockIdx.x * 256 + threadIdx.x;
    float v = cb[i];
    _Float16 h = (_Float16)v;
    ch[i] = h;
    cl[i] = (_Float16)((v - (float)h) * 1024.f);
}

// ---------------------------------------------------------------------------
// VQ distance GEMM v4: fp16 split MFMA.
// Grid (x=256 code-blocks, y=64 row-blocks); block 256 rows x 32 codes;
// wave = 64 rows x 32 codes -> acc = 4rt x 2ct x 2 sets = 64 VGPRs
// (3 waves/SIMD; fixes r8's >256-reg occupancy collapse).
// LDS frags lane-linear: frag e = (pl*2+ct)*64 + lane -> wave ds_read_b128
// sweeps 1 KB contiguous = conflict-free. Double-buffered, 1 frag/thread.
// ---------------------------------------------------------------------------
__global__ __launch_bounds__(256)
void vq_mfma_kernel(const _Float16* __restrict__ zh, const _Float16* __restrict__ zl,
                    const _Float16* __restrict__ ch, const _Float16* __restrict__ cl,
                    const float* __restrict__ cn,
                    unsigned long long* __restrict__ keys)   // [16384]
{
    __shared__ _Float16 sB[2][256 * 8];   // 8 KB total

    const int tid = threadIdx.x;
    const int lane = tid & 63;
    const int wave = tid >> 6;
    const int n16 = lane & 15;
    const int quad = lane >> 4;

    const int code0 = blockIdx.x * 32;
    const int row0 = blockIdx.y * 256 + wave * 64;

    floatx4 acc1[4][2], acc2[4][2];
#pragma unroll
    for (int rt = 0; rt < 4; rt++)
#pragma unroll
        for (int ct = 0; ct < 2; ct++) {
            acc1[rt][ct] = (floatx4){0.f, 0.f, 0.f, 0.f};
            acc2[rt][ct] = (floatx4){0.f, 0.f, 0.f, 0.f};
        }

    const _Float16* pzh = zh + (size_t)(row0 + n16) * 512 + quad * 8;
    const _Float16* pzl = zl + (size_t)(row0 + n16) * 512 + quad * 8;

    // staging: 1 frag/thread.  e=tid: pl=e>>7, ct=(e>>6)&1, quad_s=(e>>4)&3, n16_s=e&15
    const int pl_s   = tid >> 7;
    const int ct_s   = (tid >> 6) & 1;
    const int quad_s = (tid >> 4) & 3;
    const int n16_s  = tid & 15;
    const _Float16* s0 = (pl_s ? cl : ch)
        + (size_t)(code0 + ct_s * 16 + n16_s) * 512 + quad_s * 8;

    *(half8*)&sB[0][tid * 8] = *(const half8*)s0;
    __syncthreads();

    for (int c = 0; c < 16; ++c) {
        const int cur = c & 1;
        const int kk = c * 32;
        half8 ah[4], al[4];
#pragma unroll
        for (int rt = 0; rt < 4; rt++) {
            ah[rt] = *(const half8*)(pzh + (size_t)rt * 8192 + kk);
            al[rt] = *(const half8*)(pzl + (size_t)rt * 8192 + kk);
        }
        half8 t0;
        if (c < 15) t0 = *(const half8*)(s0 + kk + 32);
#pragma unroll
        for (int ct = 0; ct < 2; ++ct) {
            half8 bh = *(const half8*)&sB[cur][(ct * 64 + lane) * 8];
            half8 bl = *(const half8*)&sB[cur][((2 + ct) * 64 + lane) * 8];
#pragma unroll
            for (int rt = 0; rt < 4; rt++) {
                acc1[rt][ct] = __builtin_amdgcn_mfma_f32_16x16x32_f16(ah[rt], bh, acc1[rt][ct], 0, 0, 0);
                acc2[rt][ct] = __builtin_amdgcn_mfma_f32_16x16x32_f16(ah[rt], bl, acc2[rt][ct], 0, 0, 0);
                acc2[rt][ct] = __builtin_amdgcn_mfma_f32_16x16x32_f16(al[rt], bh, acc2[rt][ct], 0, 0, 0);
            }
        }
        if (c < 15) {
            *(half8*)&sB[cur ^ 1][tid * 8] = t0;
        }
        __syncthreads();
    }

#pragma unroll
    for (int rt = 0; rt < 4; rt++) {
#pragma unroll
        for (int reg = 0; reg < 4; reg++) {
            float best = 3.0e38f;
            int bcode = 0;
#pragma unroll
            for (int ct = 0; ct < 2; ct++) {
                const int code = code0 + ct * 16 + n16;
                float dot = acc1[rt][ct][reg] + acc2[rt][ct][reg] * (1.0f / 1024.0f);
                float s = cn[code] - 2.0f * dot;
                if (s < best) { best = s; bcode = code; }
            }
            unsigned u = __float_as_uint(best);
            u = (u & 0x80000000u) ? ~u : (u | 0x80000000u);
            unsigned long long key = ((unsigned long long)u << 32) | (unsigned)bcode;
#pragma unroll
            for (int m = 1; m < 16; m <<= 1) {
                unsigned long long o = __shfl_xor(key, m, 64);
                key = (o < key) ? o : key;
            }
            if (n16 == 0)
                atomicMin(&keys[row0 + rt * 16 + quad * 4 + reg], key);
        }
    }
}

// ---------------------------------------------------------------------------
// Gather: indices (float) into d_out tail, zq as bf16 NHWC [16,32,32,512].
// ---------------------------------------------------------------------------
__global__ __launch_bounds__(256)
void vq_gather_kernel(const unsigned long long* __restrict__ keys,
                      const float* __restrict__ cb,
                      unsigned short* __restrict__ zq, float* __restrict__ idx_out)
{
    __shared__ int sidx[64];
    const int t = threadIdx.x;
    const int v0 = blockIdx.x * 64;
    if (t < 64) {
        int idx = (int)(keys[v0 + t] & 0xFFFFFFFFull);
        sidx[t] = idx;
        idx_out[v0 + t] = (float)idx;
    }
    __syncthreads();
    const int tv = t >> 2;
    const int q = t & 3;
    const float* crow = cb + (size_t)sidx[tv] * 512;
    unsigned short* zrow = zq + (size_t)(v0 + tv) * 512;
    for (int c = q * 8; c < 512; c += 32) {
        float4 f0 = *(const float4*)(crow + c);
        float4 f1 = *(const float4*)(crow + c + 4);
        short8 h;
        h[0] = (short)f2bf(f0.x); h[1] = (short)f2bf(f0.y);
        h[2] = (short)f2bf(f0.z); h[3] = (short)f2bf(f0.w);
        h[4] = (short)f2bf(f1.x); h[5] = (short)f2bf(f1.y);
        h[6] = (short)f2bf(f1.z); h[7] = (short)f2bf(f1.w);
        *(short8*)(zrow + c) = h;
    }
}

// ---------------------------------------------------------------------------
// Deconv weight prepack: torch [CI][CO][3][3] f32 -> [tap][CO][CI] bf16
// ---------------------------------------------------------------------------
template<int CI, int CO>
__global__ __launch_bounds__(256)
void prepack_kernel(const float* __restrict__ w, unsigned short* __restrict__ wp)
{
    int i = blockIdx.x * 256 + threadIdx.x;
    if (i >= 9 * CO * CI) return;
    int ci = i / (CO * 9);
    int r  = i % (CO * 9);
    int co = r / 9;
    int tp = r % 9;
    wp[((size_t)tp * CO + co) * CI + ci] = f2bf(w[i]);
}

// ---------------------------------------------------------------------------
// MFMA ConvTranspose2d k=3 s=2 p=1 op=1 + ReLU, bf16.
// ---------------------------------------------------------------------------
template<int CIN, int COUT, int IH, int IW, bool OUT_NCHW>
__global__ __launch_bounds__(256)
void deconv_mfma_kernel(const unsigned short* __restrict__ in,   // NHWC bf16
                        const unsigned short* __restrict__ wp,   // [9][CO][CI] bf16
                        const float* __restrict__ bias,
                        unsigned short* __restrict__ out)        // bf16
{
    constexpr int OH = 2 * IH, OW = 2 * IW;
    __shared__ short sIn[5][17][40];

    const int tid = threadIdx.x;
    const int lane = tid & 63;
    const int wave = tid >> 6;
    const int n16 = lane & 15;
    const int quad = lane >> 4;

    constexpr int NTX = IW / 16;
    const int x0 = (blockIdx.x % NTX) * 16;
    const int y0 = (blockIdx.x / NTX) * 4;
    const int co0 = blockIdx.y * 64 + wave * 16;
    const int img = blockIdx.z;

    const unsigned short* inN = in + (size_t)img * IH * IW * CIN;

    floatx4 acc[4][4];
#pragma unroll
    for (int s = 0; s < 4; s++)
#pragma unroll
        for (int c = 0; c < 4; c++) acc[s][c] = (floatx4){0.f, 0.f, 0.f, 0.f};

    for (int k0 = 0; k0 < CIN; k0 += 32) {
        __syncthreads();
        for (int e = tid; e < 340; e += 256) {
            int yy = e / 68, r = e % 68;
            int xx = r >> 2, q4 = r & 3;
            int gy = y0 + yy, gx = x0 + xx;
            short8 v = {0, 0, 0, 0, 0, 0, 0, 0};
            if (gy < IH && gx < IW)
                v = *(const short8*)(inN + ((size_t)(gy * IW + gx) * CIN + k0 + q4 * 8));
            *(short8*)&sIn[yy][xx][q4 * 8] = v;
        }
        __syncthreads();

        short8 a[9];
#pragma unroll
        for (int tp = 0; tp < 9; tp++)
            a[tp] = *(const short8*)(wp + ((size_t)(tp * COUT + co0 + n16) * CIN + k0 + quad * 8));

#pragma unroll
        for (int s = 0; s < 4; s++) {
            short8 b00 = *(const short8*)&sIn[s    ][n16    ][quad * 8];
            short8 b01 = *(const short8*)&sIn[s    ][n16 + 1][quad * 8];
            short8 b10 = *(const short8*)&sIn[s + 1][n16    ][quad * 8];
            short8 b11 = *(const short8*)&sIn[s + 1][n16 + 1][quad * 8];
            acc[s][0] = __builtin_amdgcn_mfma_f32_16x16x32_bf16(a[4], b00, acc[s][0], 0, 0, 0);
            acc[s][1] = __builtin_amdgcn_mfma_f32_16x16x32_bf16(a[3], b01, acc[s][1], 0, 0, 0);
            acc[s][1] = __builtin_amdgcn_mfma_f32_16x16x32_bf16(a[5], b00, acc[s][1], 0, 0, 0);
            acc[s][2] = __builtin_amdgcn_mfma_f32_16x16x32_bf16(a[1], b10, acc[s][2], 0, 0, 0);
            acc[s][2] = __builtin_amdgcn_mfma_f32_16x16x32_bf16(a[7], b00, acc[s][2], 0, 0, 0);
            acc[s][3] = __builtin_amdgcn_mfma_f32_16x16x32_bf16(a[0], b11, acc[s][3], 0, 0, 0);
            acc[s][3] = __builtin_amdgcn_mfma_f32_16x16x32_bf16(a[2], b10, acc[s][3], 0, 0, 0);
            acc[s][3] = __builtin_amdgcn_mfma_f32_16x16x32_bf16(a[6], b01, acc[s][3], 0, 0, 0);
            acc[s][3] = __builtin_amdgcn_mfma_f32_16x16x32_bf16(a[8], b00, acc[s][3], 0, 0, 0);
        }
    }

    const float4 bv = *(const float4*)&bias[co0 + quad * 4];
    const float bb[4] = {bv.x, bv.y, bv.z, bv.w};
    const int x = x0 + n16;

    if (!OUT_NCHW) {
        unsigned short* outN = out + (size_t)img * OH * OW * COUT;
#pragma unroll
        for (int s = 0; s < 4; s++) {
            const int y = y0 + s;
#pragma unroll
            for (int c = 0; c < 4; c++) {
                const int oy = 2 * y + (c >> 1);
                const int ox = 2 * x + (c & 1);
                ushort4 h;
                h.x = f2bf(fmaxf(acc[s][c][0] + bb[0], 0.f));
                h.y = f2bf(fmaxf(acc[s][c][1] + bb[1], 0.f));
                h.z = f2bf(fmaxf(acc[s][c][2] + bb[2], 0.f));
                h.w = f2bf(fmaxf(acc[s][c][3] + bb[3], 0.f));
                *(ushort4*)(outN + ((size_t)(oy * OW + ox) * COUT + co0 + quad * 4)) = h;
            }
        }
    } else {
#pragma unroll
        for (int s = 0; s < 4; s++) {
            const int y = y0 + s;
#pragma unroll
            for (int r = 0; r < 4; r++) {
                const int co = co0 + quad * 4 + r;
                unsigned short* oC = out + (size_t)(img * COUT + co) * OH * OW;
                unsigned p0 = (unsigned)f2bf(fmaxf(acc[s][0][r] + bb[r], 0.f)) |
                              ((unsigned)f2bf(fmaxf(acc[s][1][r] + bb[r], 0.f)) << 16);
                unsigned p1 = (unsigned)f2bf(fmaxf(acc[s][2][r] + bb[r], 0.f)) |
                              ((unsigned)f2bf(fmaxf(acc[s][3][r] + bb[r], 0.f)) << 16);
                *(unsigned*)(oC + (size_t)(2 * y) * OW + 2 * x) = p0;
                *(unsigned*)(oC + (size_t)(2 * y + 1) * OW + 2 * x) = p1;
            }
        }
    }
}

// ---------------------------------------------------------------------------
// Final conv 64->3 + sigmoid. NCHW bf16 input, fp32 out (d_out).
// ---------------------------------------------------------------------------
__global__ __launch_bounds__(256)
void conv_out_kernel(const unsigned short* __restrict__ in, // [16,64,256,256] bf16
                     const float* __restrict__ w,           // [3,64,3,3]
                     const float* __restrict__ bias,
                     float* __restrict__ out)               // [16,3,256,256]
{
    constexpr int TIC = 4;
    __shared__ float s_in[TIC][3][258];
    const int t = threadIdx.x;
    const int y = blockIdx.x;
    const int n = blockIdx.y;
    const unsigned short* inN = in + (size_t)n * 64 * 65536;
    float acc0 = bias[0], acc1 = bias[1], acc2 = bias[2];

    for (int c0 = 0; c0 < 64; c0 += TIC) {
        for (int e = t; e < TIC * 3 * 258; e += 256) {
            int ci = e / 774;
            int r  = e % 774;
            int ry = r / 258, xx = r % 258;
            int gy = y - 1 + ry, gx = xx - 1;
            float v = 0.f;
            if ((unsigned)gy < 256u && (unsigned)gx < 256u)
                v = bf2f(inN[(size_t)(c0 + ci) * 65536 + gy * 256 + gx]);
            s_in[ci][ry][xx] = v;
        }
        __syncthreads();
#pragma unroll
        for (int ci = 0; ci < TIC; ++ci) {
            float iv[3][3];
#pragma unroll
            for (int ry = 0; ry < 3; ry++)
#pragma unroll
                for (int kx = 0; kx < 3; kx++)
                    iv[ry][kx] = s_in[ci][ry][t + kx];
#pragma unroll
            for (int k = 0; k < 9; k++) {
                const float v = iv[k / 3][k % 3];
                acc0 += w[(0 * 64 + c0 + ci) * 9 + k] * v;
                acc1 += w[(1 * 64 + c0 + ci) * 9 + k] * v;
                acc2 += w[(2 * 64 + c0 + ci) * 9 + k] * v;
            }
        }
        __syncthreads();
    }
    const size_t o = (size_t)((n * 3 + 0) * 256 + y) * 256 + t;
    out[o]          = 1.f / (1.f + __expf(-acc0));
    out[o + 65536]  = 1.f / (1.f + __expf(-acc1));
    out[o + 131072] = 1.f / (1.f + __expf(-acc2));
}

// ---------------------------------------------------------------------------
// Workspace (peak 201.5 MB) — same layout as rounds 6-8.
// ---------------------------------------------------------------------------
extern "C" void kernel_launch(void* const* d_in, const int* in_sizes, int n_in,
                              void* d_out, int out_size, void* d_ws, size_t ws_size,
                              hipStream_t stream)
{
    const float* x   = (const float*)d_in[0];
    const float* w1  = (const float*)d_in[1];
    const float* b1  = (const float*)d_in[2];
    const float* w2  = (const float*)d_in[3];
    const float* b2  = (const float*)d_in[4];
    const float* w3  = (const float*)d_in[5];
    const float* b3  = (const float*)d_in[6];
    const float* w4  = (const float*)d_in[7];
    const float* b4  = (const float*)d_in[8];
    const float* cb  = (const float*)d_in[9];
    const float* d1w = (const float*)d_in[10];
    const float* d1b = (const float*)d_in[11];
    const float* d2w = (const float*)d_in[12];
    const float* d2b = (const float*)d_in[13];
    const float* d3w = (const float*)d_in[14];
    const float* d3b = (const float*)d_in[15];
    const float* wo  = (const float*)d_in[16];
    const float* bo  = (const float*)d_in[17];

    char* ws = (char*)d_ws;
    _Float16* H2H = (_Float16*)(ws);
    _Float16* H2L = (_Float16*)(ws + 67108864);
    _Float16* H3H = (_Float16*)(ws + 134217728);
    _Float16* H3L = (_Float16*)(ws + 167772160);
    _Float16* ZH  = (_Float16*)(ws);
    _Float16* ZL  = (_Float16*)(ws + 16777216);
    unsigned short* ZQ = (unsigned short*)(ws + 33554432);
    _Float16* CBH = (_Float16*)(ws + 50331648);
    _Float16* CBL = (_Float16*)(ws + 58720256);
    unsigned short* G1 = (unsigned short*)(ws + 67108864);
    unsigned short* G2 = (unsigned short*)(ws + 134217728);
    unsigned short* G3 = (unsigned short*)(ws);
    unsigned long long* keys = (unsigned long long*)(ws + 201326592);
    float* cn = (float*)(ws + 201326592 + 131072);

    char* oscratch = (char*)d_out;
    _Float16* EW3H = (_Float16*)(oscratch);
    _Float16* EW3L = (_Float16*)(oscratch + 589824);
    _Float16* EW4H = (_Float16*)(oscratch + 1179648);
    _Float16* EW4L = (_Float16*)(oscratch + 3538944);
    unsigned short* WP1 = (unsigned short*)(oscratch + 5898240);
    unsigned short* WP2 = (unsigned short*)(oscratch + 8257536);
    unsigned short* WP3 = (unsigned short*)(oscratch + 8847360);
    _Float16* EW2H = (_Float16*)(oscratch + 8994816);
    _Float16* EW2L = (_Float16*)(oscratch + 9142272);

    float* xrec = (float*)d_out;
    float* idxf = (float*)d_out + (size_t)16 * 3 * 256 * 256;

    // ---- weight prepacks ----
    prepack_conv_kernel<64,  128><<<288,  256, 0, stream>>>(w2, EW2H, EW2L);
    prepack_conv_kernel<128, 256><<<1152, 256, 0, stream>>>(w3, EW3H, EW3L);
    prepack_conv_kernel<256, 512><<<4608, 256, 0, stream>>>(w4, EW4H, EW4L);
    prepack_kernel<512, 256><<<4608, 256, 0, stream>>>(d1w, WP1);
    prepack_kernel<256, 128><<<1152, 256, 0, stream>>>(d2w, WP2);
    prepack_kernel<128, 64 ><<<288,  256, 0, stream>>>(d3w, WP3);

    // ---- encoder ----
    fused_conv12_mfma_kernel<<<dim3(256, 2, 16), 256, 0, stream>>>(x, w1, b1, EW2H, EW2L, b2, H2H, H2L);
    conv_mfma_kernel<128, 256, 128, 128, true ><<<dim3(64, 4, 16), 256, 0, stream>>>(H2H, H2L, EW3H, EW3L, b3, H3H, H3L);
    conv_mfma_kernel<256, 512, 64,  64,  false><<<dim3(16, 8, 16), 256, 0, stream>>>(H3H, H3L, EW4H, EW4L, b4, ZH, ZL);

    // ---- VQ ----
    cnorm_kernel<<<8192, 64, 0, stream>>>(cb, cn);
    init_keys_kernel<<<64, 256, 0, stream>>>(keys);
    split_cb_kernel<<<16384, 256, 0, stream>>>(cb, CBH, CBL);
    vq_mfma_kernel<<<dim3(256, 64), 256, 0, stream>>>(ZH, ZL, CBH, CBL, cn, keys);
    vq_gather_kernel<<<256, 256, 0, stream>>>(keys, cb, ZQ, idxf);

    // ---- decoder (bf16 MFMA) ----
    deconv_mfma_kernel<512, 256, 32,  32,  false><<<dim3(16,  4, 16), 256, 0, stream>>>(ZQ, WP1, d1b, G1);
    deconv_mfma_kernel<256, 128, 64,  64,  false><<<dim3(64,  2, 16), 256, 0, stream>>>(G1, WP2, d2b, G2);
    deconv_mfma_kernel<128, 64,  128, 128, true ><<<dim3(256, 1, 16), 256, 0, stream>>>(G2, WP3, d3b, G3);
    conv_out_kernel<<<dim3(256, 16), 256, 0, stream>>>(G3, wo, bo, xrec);
}

// Round 11
// 2310.250 us; speedup vs baseline: 1.1539x; 1.1185x over previous
//
#include <hip/hip_runtime.h>
#include <cstddef>

typedef short short8 __attribute__((ext_vector_type(8)));
typedef _Float16 half8 __attribute__((ext_vector_type(8)));
typedef _Float16 half4 __attribute__((ext_vector_type(4)));
typedef _Float16 half2v __attribute__((ext_vector_type(2)));
typedef float floatx4 __attribute__((ext_vector_type(4)));

// ---- bf16 helpers (round-to-nearest-even) ---------------------------------
__device__ __forceinline__ unsigned short f2bf(float f) {
    unsigned u = __float_as_uint(f);
    u += 0x7FFFu + ((u >> 16) & 1u);
    return (unsigned short)(u >> 16);
}
__device__ __forceinline__ float bf2f(unsigned short h) {
    return __uint_as_float((unsigned)h << 16);
}

// ---------------------------------------------------------------------------
// Fused conv1(3->64,s1,relu) + conv2(64->128,s2,relu):
// conv1 inline fp32 (rolling x-window regs), conv2 split-fp16 MFMA.
// ---------------------------------------------------------------------------
__global__ __launch_bounds__(256)
void fused_conv12_mfma_kernel(const float* __restrict__ x,   // [16,3,256,256]
                              const float* __restrict__ w1,  // [64,3,3,3]
                              const float* __restrict__ b1,
                              const _Float16* __restrict__ w2h, // [9][128][64]
                              const _Float16* __restrict__ w2l,
                              const float* __restrict__ b2,
                              _Float16* __restrict__ outH,   // NHWC [16,128,128,128]
                              _Float16* __restrict__ outL)
{
    __shared__ float s_x[3][11][36];
    __shared__ _Float16 sE[2][9][17][40];   // [plane][row][x/2][ci pad 40]
    __shared__ _Float16 sO[2][9][16][40];

    const int tid = threadIdx.x;
    const int lane = tid & 63;
    const int wave = tid >> 6;
    const int n16 = lane & 15;
    const int quad = lane >> 4;

    const int ox0 = (blockIdx.x & 7) * 16;    // 128/16
    const int oy0 = (blockIdx.x >> 3) * 4;    // 32 y-tiles
    const int co0 = blockIdx.y * 64 + wave * 16;
    const int img = blockIdx.z;

    const int hy0 = oy0 * 2 - 1, hx0 = ox0 * 2 - 1;   // h1 tile origin (9x33)
    const int gy0 = hy0 - 1,     gx0 = hx0 - 1;       // x patch origin (11x35)
    const float* xN = x + (size_t)img * 3 * 65536;

    for (int e = tid; e < 3 * 11 * 35; e += 256) {
        int c = e / 385, r = e % 385;
        int yy = r / 35, xx = r % 35;
        int gy = gy0 + yy, gx = gx0 + xx;
        float v = 0.f;
        if ((unsigned)gy < 256u && (unsigned)gx < 256u)
            v = xN[(size_t)c * 65536 + gy * 256 + gx];
        s_x[c][yy][xx] = v;
    }

    floatx4 acc1[4], acc2[4];
#pragma unroll
    for (int s = 0; s < 4; s++) {
        acc1[s] = (floatx4){0.f, 0.f, 0.f, 0.f};
        acc2[s] = (floatx4){0.f, 0.f, 0.f, 0.f};
    }

    const int pair = tid & 15;
    const int pxg  = tid >> 4;

    for (int c0 = 0; c0 < 64; c0 += 32) {
        __syncthreads();

        const int ch0 = c0 + pair * 2;
        float wA[27], wB[27];
#pragma unroll
        for (int k = 0; k < 27; k++) {
            wA[k] = w1[ch0 * 27 + k];
            wB[k] = w1[ch0 * 27 + 27 + k];
        }
        const float bA = b1[ch0], bB = b1[ch0 + 1];

        for (int px = pxg; px < 33; px += 16) {
            const bool colok = (unsigned)(hx0 + px) < 256u;
            float xw[3][3][3];
#pragma unroll
            for (int c = 0; c < 3; c++)
#pragma unroll
                for (int r = 0; r < 3; r++)
#pragma unroll
                    for (int kx = 0; kx < 3; kx++)
                        xw[c][r][kx] = s_x[c][r][px + kx];
#pragma unroll
            for (int py = 0; py < 9; py++) {
                const bool inb = colok && (unsigned)(hy0 + py) < 256u;
                float aA = bA, aB = bB;
#pragma unroll
                for (int c = 0; c < 3; c++)
#pragma unroll
                    for (int k = 0; k < 9; k++) {
                        const float xv = xw[c][k / 3][k % 3];
                        aA += wA[c * 9 + k] * xv;
                        aB += wB[c * 9 + k] * xv;
                    }
                float vA = inb ? fmaxf(aA, 0.f) : 0.f;
                float vB = inb ? fmaxf(aB, 0.f) : 0.f;
                half2v hv, lv;
                _Float16 hA = (_Float16)vA, hB = (_Float16)vB;
                hv[0] = hA; hv[1] = hB;
                lv[0] = (_Float16)((vA - (float)hA) * 1024.f);
                lv[1] = (_Float16)((vB - (float)hB) * 1024.f);
                _Float16* dH = (px & 1) ? &sO[0][py][px >> 1][pair * 2]
                                        : &sE[0][py][px >> 1][pair * 2];
                _Float16* dL = (px & 1) ? &sO[1][py][px >> 1][pair * 2]
                                        : &sE[1][py][px >> 1][pair * 2];
                *(half2v*)dH = hv;
                *(half2v*)dL = lv;
                if (py < 8) {
#pragma unroll
                    for (int c = 0; c < 3; c++) {
#pragma unroll
                        for (int r = 0; r < 2; r++)
#pragma unroll
                            for (int kx = 0; kx < 3; kx++)
                                xw[c][r][kx] = xw[c][r + 1][kx];
#pragma unroll
                        for (int kx = 0; kx < 3; kx++)
                            xw[c][2][kx] = s_x[c][py + 3][px + kx];
                    }
                }
            }
        }
        __syncthreads();

        half8 ah[9], al[9];
#pragma unroll
        for (int tp = 0; tp < 9; tp++) {
            size_t o = ((size_t)(tp * 128 + co0 + n16)) * 64 + c0 + quad * 8;
            ah[tp] = *(const half8*)(w2h + o);
            al[tp] = *(const half8*)(w2l + o);
        }
#pragma unroll
        for (int oy = 0; oy < 4; oy++) {
#pragma unroll
            for (int tp = 0; tp < 9; tp++) {
                const int kx = tp % 3;
                const int row = oy * 2 + tp / 3;
                half8 bh, bl;
                if (kx == 0)      { bh = *(const half8*)&sE[0][row][n16][quad * 8];
                                    bl = *(const half8*)&sE[1][row][n16][quad * 8]; }
                else if (kx == 1) { bh = *(const half8*)&sO[0][row][n16][quad * 8];
                                    bl = *(const half8*)&sO[1][row][n16][quad * 8]; }
                else              { bh = *(const half8*)&sE[0][row][n16 + 1][quad * 8];
                                    bl = *(const half8*)&sE[1][row][n16 + 1][quad * 8]; }
                acc1[oy] = __builtin_amdgcn_mfma_f32_16x16x32_f16(ah[tp], bh, acc1[oy], 0, 0, 0);
                acc2[oy] = __builtin_amdgcn_mfma_f32_16x16x32_f16(ah[tp], bl, acc2[oy], 0, 0, 0);
                acc2[oy] = __builtin_amdgcn_mfma_f32_16x16x32_f16(al[tp], bh, acc2[oy], 0, 0, 0);
            }
        }
    }

    const float4 bv = *(const float4*)&b2[co0 + quad * 4];
    const float bb[4] = {bv.x, bv.y, bv.z, bv.w};
#pragma unroll
    for (int oy = 0; oy < 4; oy++) {
        half4 hv, lv;
#pragma unroll
        for (int r = 0; r < 4; r++) {
            float v = fmaxf(acc1[oy][r] + acc2[oy][r] * (1.0f / 1024.0f) + bb[r], 0.f);
            _Float16 h = (_Float16)v;
            hv[r] = h;
            lv[r] = (_Float16)((v - (float)h) * 1024.f);
        }
        size_t o = (((size_t)img * 128 + (oy0 + oy)) * 128 + (ox0 + n16)) * 128
                   + co0 + quad * 4;
        *(half4*)(outH + o) = hv;
        *(half4*)(outL + o) = lv;
    }
}

// ---------------------------------------------------------------------------
// Encoder conv weight prepack: OIHW f32 -> [tap][CO][CI] fp16 hi + lo*1024
// ---------------------------------------------------------------------------
template<int CI, int CO>
__global__ __launch_bounds__(256)
void prepack_conv_kernel(const float* __restrict__ w,
                         _Float16* __restrict__ wh, _Float16* __restrict__ wl)
{
    int i = blockIdx.x * 256 + threadIdx.x;
    if (i >= CO * CI * 9) return;
    int co = i / (CI * 9);
    int r  = i % (CI * 9);
    int ci = r / 9;
    int tp = r % 9;
    float v = w[i];
    _Float16 h = (_Float16)v;
    size_t o = ((size_t)tp * CO + co) * CI + ci;
    wh[o] = h;
    wl[o] = (_Float16)((v - (float)h) * 1024.f);
}

// ---------------------------------------------------------------------------
// Split-precision fp16 MFMA 3x3 conv, stride 2, pad 1.  NHWC hi/lo in & out.
// ---------------------------------------------------------------------------
template<int CIN, int COUT, int IH, int IW, bool RELU>
__global__ __launch_bounds__(256)
void conv_mfma_kernel(const _Float16* __restrict__ inH, const _Float16* __restrict__ inL,
                      const _Float16* __restrict__ wpH, const _Float16* __restrict__ wpL,
                      const float* __restrict__ bias,
                      _Float16* __restrict__ outH, _Float16* __restrict__ outL)
{
    constexpr int OH = IH / 2, OW = IW / 2;
    __shared__ _Float16 sE[2][9][17][40];
    __shared__ _Float16 sO[2][9][16][40];

    const int tid = threadIdx.x;
    const int lane = tid & 63;
    const int wave = tid >> 6;
    const int n16 = lane & 15;
    const int quad = lane >> 4;

    constexpr int NTX = OW / 16;
    const int ox0 = (blockIdx.x % NTX) * 16;
    const int oy0 = (blockIdx.x / NTX) * 4;
    const int co0 = blockIdx.y * 64 + wave * 16;
    const int img = blockIdx.z;

    const int iy0 = oy0 * 2 - 1;
    const int ix0 = ox0 * 2 - 1;
    const _Float16* iNH = inH + (size_t)img * IH * IW * CIN;
    const _Float16* iNL = inL + (size_t)img * IH * IW * CIN;

    floatx4 acc1[4], acc2[4];
#pragma unroll
    for (int s = 0; s < 4; s++) {
        acc1[s] = (floatx4){0.f, 0.f, 0.f, 0.f};
        acc2[s] = (floatx4){0.f, 0.f, 0.f, 0.f};
    }

    for (int k0 = 0; k0 < CIN; k0 += 32) {
        __syncthreads();
        for (int e = tid; e < 2376; e += 256) {
            int pl = e / 1188;
            int r  = e % 1188;
            int pix = r >> 2, q = r & 3;
            int py = pix / 33, px = pix % 33;
            int iy = iy0 + py, ix = ix0 + px;
            half8 v = (half8)(_Float16)0;
            if ((unsigned)iy < (unsigned)IH && (unsigned)ix < (unsigned)IW)
                v = *(const half8*)((pl ? iNL : iNH) + ((size_t)(iy * IW + ix) * CIN + k0 + q * 8));
            if (px & 1) *(half8*)&sO[pl][py][px >> 1][q * 8] = v;
            else        *(half8*)&sE[pl][py][px >> 1][q * 8] = v;
        }
        __syncthreads();

        half8 ah[9], al[9];
#pragma unroll
        for (int tp = 0; tp < 9; tp++) {
            size_t o = ((size_t)(tp * COUT + co0 + n16)) * CIN + k0 + quad * 8;
            ah[tp] = *(const half8*)(wpH + o);
            al[tp] = *(const half8*)(wpL + o);
        }

#pragma unroll
        for (int oy = 0; oy < 4; oy++) {
#pragma unroll
            for (int tp = 0; tp < 9; tp++) {
                const int ky = tp / 3, kx = tp % 3;
                const int row = oy * 2 + ky;
                half8 bh, bl;
                if (kx == 0)      { bh = *(const half8*)&sE[0][row][n16][quad * 8];
                                    bl = *(const half8*)&sE[1][row][n16][quad * 8]; }
                else if (kx == 1) { bh = *(const half8*)&sO[0][row][n16][quad * 8];
                                    bl = *(const half8*)&sO[1][row][n16][quad * 8]; }
                else              { bh = *(const half8*)&sE[0][row][n16 + 1][quad * 8];
                                    bl = *(const half8*)&sE[1][row][n16 + 1][quad * 8]; }
                acc1[oy] = __builtin_amdgcn_mfma_f32_16x16x32_f16(ah[tp], bh, acc1[oy], 0, 0, 0);
                acc2[oy] = __builtin_amdgcn_mfma_f32_16x16x32_f16(ah[tp], bl, acc2[oy], 0, 0, 0);
                acc2[oy] = __builtin_amdgcn_mfma_f32_16x16x32_f16(al[tp], bh, acc2[oy], 0, 0, 0);
            }
        }
    }

    const float4 bv = *(const float4*)&bias[co0 + quad * 4];
    const float bb[4] = {bv.x, bv.y, bv.z, bv.w};
#pragma unroll
    for (int oy = 0; oy < 4; oy++) {
        half4 hv, lv;
#pragma unroll
        for (int r = 0; r < 4; r++) {
            float v = acc1[oy][r] + acc2[oy][r] * (1.0f / 1024.0f) + bb[r];
            if (RELU) v = fmaxf(v, 0.f);
            _Float16 h = (_Float16)v;
            hv[r] = h;
            lv[r] = (_Float16)((v - (float)h) * 1024.f);
        }
        size_t o = (((size_t)img * OH + (oy0 + oy)) * OW + (ox0 + n16)) * COUT
                   + co0 + quad * 4;
        *(half4*)(outH + o) = hv;
        *(half4*)(outL + o) = lv;
    }
}

// ---------------------------------------------------------------------------
__global__ __launch_bounds__(64)
void cnorm_kernel(const float* __restrict__ cb, float* __restrict__ cn)
{
    const int code = blockIdx.x;
    const int t = threadIdx.x;
    const float* row = cb + (size_t)code * 512;
    float s = 0.f;
    for (int i = t; i < 512; i += 64) s += row[i] * row[i];
#pragma unroll
    for (int off = 32; off > 0; off >>= 1) s += __shfl_down(s, off, 64);
    if (t == 0) cn[code] = s;
}

__global__ __launch_bounds__(256)
void init_keys_kernel(unsigned long long* __restrict__ keys)
{
    keys[blockIdx.x * 256 + threadIdx.x] = ~0ull;
}

// ---------------------------------------------------------------------------
__global__ __launch_bounds__(256)
void split_cb_kernel(const float* __restrict__ cb,
                     _Float16* __restrict__ ch, _Float16* __restrict__ cl)
{
    size_t i = (size_t)blockIdx.x * 256 + threadIdx.x;
    float v = cb[i];
    _Float16 h = (_Float16)v;
    ch[i] = h;
    cl[i] = (_Float16)((v - (float)h) * 1024.f);
}

// ---------------------------------------------------------------------------
// VQ distance GEMM v5b: fp16 split MFMA (R10 with A-buffer index fix).
// Grid (x=128 code-blocks, y=128 row-blocks); block 128 rows x 64 codes;
// wave = 32 rows (rt=2) x 64 codes (ct=4): acc = 64 VGPRs.
// A regs double-buffered As[buf] = {hi_rt0, hi_rt1, lo_rt0, lo_rt1};
// consumed as As[cur][rt] (hi) and As[cur][2+rt] (lo)  <-- R10 bug fixed.
// B lane-linear conflict-free LDS, double-buffered.
// ---------------------------------------------------------------------------
__global__ __launch_bounds__(256)
void vq_mfma_kernel(const _Float16* __restrict__ zh, const _Float16* __restrict__ zl,
                    const _Float16* __restrict__ ch, const _Float16* __restrict__ cl,
                    const float* __restrict__ cn,
                    unsigned long long* __restrict__ keys)   // [16384]
{
    __shared__ _Float16 sB[2][512 * 8];   // 16 KB; frag e=(pl*4+ct)*64+lane

    const int tid = threadIdx.x;
    const int lane = tid & 63;
    const int wave = tid >> 6;
    const int n16 = lane & 15;
    const int quad = lane >> 4;

    const int code0 = blockIdx.x * 64;
    const int row0 = blockIdx.y * 128 + wave * 32;

    floatx4 acc1[2][4], acc2[2][4];
#pragma unroll
    for (int rt = 0; rt < 2; rt++)
#pragma unroll
        for (int ct = 0; ct < 4; ct++) {
            acc1[rt][ct] = (floatx4){0.f, 0.f, 0.f, 0.f};
            acc2[rt][ct] = (floatx4){0.f, 0.f, 0.f, 0.f};
        }

    const _Float16* pzh = zh + (size_t)(row0 + n16) * 512 + quad * 8;
    const _Float16* pzl = zl + (size_t)(row0 + n16) * 512 + quad * 8;

    // B staging: 2 frags/thread, e0=tid (hi plane), e1=tid+256 (lo plane).
    const _Float16* s0 = ch
        + (size_t)(code0 + ((tid >> 6) & 3) * 16 + (tid & 15)) * 512 + ((tid >> 4) & 3) * 8;
    const _Float16* s1 = cl
        + (size_t)(code0 + ((tid >> 6) & 3) * 16 + (tid & 15)) * 512 + ((tid >> 4) & 3) * 8;

    // A register double-buffer: [buf] = {hi_rt0, hi_rt1, lo_rt0, lo_rt1}
    half8 As[2][4];
    As[0][0] = *(const half8*)(pzh);
    As[0][1] = *(const half8*)(pzh + 8192);
    As[0][2] = *(const half8*)(pzl);
    As[0][3] = *(const half8*)(pzl + 8192);
    *(half8*)&sB[0][tid * 8]         = *(const half8*)s0;
    *(half8*)&sB[0][(tid + 256) * 8] = *(const half8*)s1;
    __syncthreads();

    for (int c = 0; c < 16; ++c) {
        const int cur = c & 1;
        const int kk = c * 32;
        half8 t0, t1;
        if (c < 15) {
            const int nxt = cur ^ 1;
            As[nxt][0] = *(const half8*)(pzh + kk + 32);
            As[nxt][1] = *(const half8*)(pzh + 8192 + kk + 32);
            As[nxt][2] = *(const half8*)(pzl + kk + 32);
            As[nxt][3] = *(const half8*)(pzl + 8192 + kk + 32);
            t0 = *(const half8*)(s0 + kk + 32);
            t1 = *(const half8*)(s1 + kk + 32);
        }
#pragma unroll
        for (int ct = 0; ct < 4; ++ct) {
            half8 bh = *(const half8*)&sB[cur][(ct * 64 + lane) * 8];
            half8 bl = *(const half8*)&sB[cur][((4 + ct) * 64 + lane) * 8];
#pragma unroll
            for (int rt = 0; rt < 2; rt++) {
                acc1[rt][ct] = __builtin_amdgcn_mfma_f32_16x16x32_f16(As[cur][rt],     bh, acc1[rt][ct], 0, 0, 0);
                acc2[rt][ct] = __builtin_amdgcn_mfma_f32_16x16x32_f16(As[cur][rt],     bl, acc2[rt][ct], 0, 0, 0);
                acc2[rt][ct] = __builtin_amdgcn_mfma_f32_16x16x32_f16(As[cur][2 + rt], bh, acc2[rt][ct], 0, 0, 0);
            }
        }
        if (c < 15) {
            const int nxt = cur ^ 1;
            *(half8*)&sB[nxt][tid * 8]         = t0;
            *(half8*)&sB[nxt][(tid + 256) * 8] = t1;
        }
        __syncthreads();
    }

#pragma unroll
    for (int rt = 0; rt < 2; rt++) {
#pragma unroll
        for (int reg = 0; reg < 4; reg++) {
            float best = 3.0e38f;
            int bcode = 0;
#pragma unroll
            for (int ct = 0; ct < 4; ct++) {
                const int code = code0 + ct * 16 + n16;
                float dot = acc1[rt][ct][reg] + acc2[rt][ct][reg] * (1.0f / 1024.0f);
                float s = cn[code] - 2.0f * dot;
                if (s < best) { best = s; bcode = code; }
            }
            unsigned u = __float_as_uint(best);
            u = (u & 0x80000000u) ? ~u : (u | 0x80000000u);
            unsigned long long key = ((unsigned long long)u << 32) | (unsigned)bcode;
#pragma unroll
            for (int m = 1; m < 16; m <<= 1) {
                unsigned long long o = __shfl_xor(key, m, 64);
                key = (o < key) ? o : key;
            }
            if (n16 == 0)
                atomicMin(&keys[row0 + rt * 16 + quad * 4 + reg], key);
        }
    }
}

// ---------------------------------------------------------------------------
// Gather: indices (float) into d_out tail, zq as bf16 NHWC [16,32,32,512].
// ---------------------------------------------------------------------------
__global__ __launch_bounds__(256)
void vq_gather_kernel(const unsigned long long* __restrict__ keys,
                      const float* __restrict__ cb,
                      unsigned short* __restrict__ zq, float* __restrict__ idx_out)
{
    __shared__ int sidx[64];
    const int t = threadIdx.x;
    const int v0 = blockIdx.x * 64;
    if (t < 64) {
        int idx = (int)(keys[v0 + t] & 0xFFFFFFFFull);
        sidx[t] = idx;
        idx_out[v0 + t] = (float)idx;
    }
    __syncthreads();
    const int tv = t >> 2;
    const int q = t & 3;
    const float* crow = cb + (size_t)sidx[tv] * 512;
    unsigned short* zrow = zq + (size_t)(v0 + tv) * 512;
    for (int c = q * 8; c < 512; c += 32) {
        float4 f0 = *(const float4*)(crow + c);
        float4 f1 = *(const float4*)(crow + c + 4);
        short8 h;
        h[0] = (short)f2bf(f0.x); h[1] = (short)f2bf(f0.y);
        h[2] = (short)f2bf(f0.z); h[3] = (short)f2bf(f0.w);
        h[4] = (short)f2bf(f1.x); h[5] = (short)f2bf(f1.y);
        h[6] = (short)f2bf(f1.z); h[7] = (short)f2bf(f1.w);
        *(short8*)(zrow + c) = h;
    }
}

// ---------------------------------------------------------------------------
// Deconv weight prepack: torch [CI][CO][3][3] f32 -> [tap][CO][CI] bf16
// ---------------------------------------------------------------------------
template<int CI, int CO>
__global__ __launch_bounds__(256)
void prepack_kernel(const float* __restrict__ w, unsigned short* __restrict__ wp)
{
    int i = blockIdx.x * 256 + threadIdx.x;
    if (i >= 9 * CO * CI) return;
    int ci = i / (CO * 9);
    int r  = i % (CO * 9);
    int co = r / 9;
    int tp = r % 9;
    wp[((size_t)tp * CO + co) * CI + ci] = f2bf(w[i]);
}

// ---------------------------------------------------------------------------
// MFMA ConvTranspose2d k=3 s=2 p=1 op=1 + ReLU, bf16.
// ---------------------------------------------------------------------------
template<int CIN, int COUT, int IH, int IW, bool OUT_NCHW>
__global__ __launch_bounds__(256)
void deconv_mfma_kernel(const unsigned short* __restrict__ in,   // NHWC bf16
                        const unsigned short* __restrict__ wp,   // [9][CO][CI] bf16
                        const float* __restrict__ bias,
                        unsigned short* __restrict__ out)        // bf16
{
    constexpr int OH = 2 * IH, OW = 2 * IW;
    __shared__ short sIn[5][17][40];

    const int tid = threadIdx.x;
    const int lane = tid & 63;
    const int wave = tid >> 6;
    const int n16 = lane & 15;
    const int quad = lane >> 4;

    constexpr int NTX = IW / 16;
    const int x0 = (blockIdx.x % NTX) * 16;
    const int y0 = (blockIdx.x / NTX) * 4;
    const int co0 = blockIdx.y * 64 + wave * 16;
    const int img = blockIdx.z;

    const unsigned short* inN = in + (size_t)img * IH * IW * CIN;

    floatx4 acc[4][4];
#pragma unroll
    for (int s = 0; s < 4; s++)
#pragma unroll
        for (int c = 0; c < 4; c++) acc[s][c] = (floatx4){0.f, 0.f, 0.f, 0.f};

    for (int k0 = 0; k0 < CIN; k0 += 32) {
        __syncthreads();
        for (int e = tid; e < 340; e += 256) {
            int yy = e / 68, r = e % 68;
            int xx = r >> 2, q4 = r & 3;
            int gy = y0 + yy, gx = x0 + xx;
            short8 v = {0, 0, 0, 0, 0, 0, 0, 0};
            if (gy < IH && gx < IW)
                v = *(const short8*)(inN + ((size_t)(gy * IW + gx) * CIN + k0 + q4 * 8));
            *(short8*)&sIn[yy][xx][q4 * 8] = v;
        }
        __syncthreads();

        short8 a[9];
#pragma unroll
        for (int tp = 0; tp < 9; tp++)
            a[tp] = *(const short8*)(wp + ((size_t)(tp * COUT + co0 + n16) * CIN + k0 + quad * 8));

#pragma unroll
        for (int s = 0; s < 4; s++) {
            short8 b00 = *(const short8*)&sIn[s    ][n16    ][quad * 8];
            short8 b01 = *(const short8*)&sIn[s    ][n16 + 1][quad * 8];
            short8 b10 = *(const short8*)&sIn[s + 1][n16    ][quad * 8];
            short8 b11 = *(const short8*)&sIn[s + 1][n16 + 1][quad * 8];
            acc[s][0] = __builtin_amdgcn_mfma_f32_16x16x32_bf16(a[4], b00, acc[s][0], 0, 0, 0);
            acc[s][1] = __builtin_amdgcn_mfma_f32_16x16x32_bf16(a[3], b01, acc[s][1], 0, 0, 0);
            acc[s][1] = __builtin_amdgcn_mfma_f32_16x16x32_bf16(a[5], b00, acc[s][1], 0, 0, 0);
            acc[s][2] = __builtin_amdgcn_mfma_f32_16x16x32_bf16(a[1], b10, acc[s][2], 0, 0, 0);
            acc[s][2] = __builtin_amdgcn_mfma_f32_16x16x32_bf16(a[7], b00, acc[s][2], 0, 0, 0);
            acc[s][3] = __builtin_amdgcn_mfma_f32_16x16x32_bf16(a[0], b11, acc[s][3], 0, 0, 0);
            acc[s][3] = __builtin_amdgcn_mfma_f32_16x16x32_bf16(a[2], b10, acc[s][3], 0, 0, 0);
            acc[s][3] = __builtin_amdgcn_mfma_f32_16x16x32_bf16(a[6], b01, acc[s][3], 0, 0, 0);
            acc[s][3] = __builtin_amdgcn_mfma_f32_16x16x32_bf16(a[8], b00, acc[s][3], 0, 0, 0);
        }
    }

    const float4 bv = *(const float4*)&bias[co0 + quad * 4];
    const float bb[4] = {bv.x, bv.y, bv.z, bv.w};
    const int x = x0 + n16;

    if (!OUT_NCHW) {
        unsigned short* outN = out + (size_t)img * OH * OW * COUT;
#pragma unroll
        for (int s = 0; s < 4; s++) {
            const int y = y0 + s;
#pragma unroll
            for (int c = 0; c < 4; c++) {
                const int oy = 2 * y + (c >> 1);
                const int ox = 2 * x + (c & 1);
                ushort4 h;
                h.x = f2bf(fmaxf(acc[s][c][0] + bb[0], 0.f));
                h.y = f2bf(fmaxf(acc[s][c][1] + bb[1], 0.f));
                h.z = f2bf(fmaxf(acc[s][c][2] + bb[2], 0.f));
                h.w = f2bf(fmaxf(acc[s][c][3] + bb[3], 0.f));
                *(ushort4*)(outN + ((size_t)(oy * OW + ox) * COUT + co0 + quad * 4)) = h;
            }
        }
    } else {
#pragma unroll
        for (int s = 0; s < 4; s++) {
            const int y = y0 + s;
#pragma unroll
            for (int r = 0; r < 4; r++) {
                const int co = co0 + quad * 4 + r;
                unsigned short* oC = out + (size_t)(img * COUT + co) * OH * OW;
                unsigned p0 = (unsigned)f2bf(fmaxf(acc[s][0][r] + bb[r], 0.f)) |
                              ((unsigned)f2bf(fmaxf(acc[s][1][r] + bb[r], 0.f)) << 16);
                unsigned p1 = (unsigned)f2bf(fmaxf(acc[s][2][r] + bb[r], 0.f)) |
                              ((unsigned)f2bf(fmaxf(acc[s][3][r] + bb[r], 0.f)) << 16);
                *(unsigned*)(oC + (size_t)(2 * y) * OW + 2 * x) = p0;
                *(unsigned*)(oC + (size_t)(2 * y + 1) * OW + 2 * x) = p1;
            }
        }
    }
}

// ---------------------------------------------------------------------------
// Final conv 64->3 + sigmoid. NCHW bf16 input, fp32 out (d_out).
// ---------------------------------------------------------------------------
__global__ __launch_bounds__(256)
void conv_out_kernel(const unsigned short* __restrict__ in, // [16,64,256,256] bf16
                     const float* __restrict__ w,           // [3,64,3,3]
                     const float* __restrict__ bias,
                     float* __restrict__ out)               // [16,3,256,256]
{
    constexpr int TIC = 4;
    __shared__ float s_in[TIC][3][258];
    const int t = threadIdx.x;
    const int y = blockIdx.x;
    const int n = blockIdx.y;
    const unsigned short* inN = in + (size_t)n * 64 * 65536;
    float acc0 = bias[0], acc1 = bias[1], acc2 = bias[2];

    for (int c0 = 0; c0 < 64; c0 += TIC) {
        for (int e = t; e < TIC * 3 * 258; e += 256) {
            int ci = e / 774;
            int r  = e % 774;
            int ry = r / 258, xx = r % 258;
            int gy = y - 1 + ry, gx = xx - 1;
            float v = 0.f;
            if ((unsigned)gy < 256u && (unsigned)gx < 256u)
                v = bf2f(inN[(size_t)(c0 + ci) * 65536 + gy * 256 + gx]);
            s_in[ci][ry][xx] = v;
        }
        __syncthreads();
#pragma unroll
        for (int ci = 0; ci < TIC; ++ci) {
            float iv[3][3];
#pragma unroll
            for (int ry = 0; ry < 3; ry++)
#pragma unroll
                for (int kx = 0; kx < 3; kx++)
                    iv[ry][kx] = s_in[ci][ry][t + kx];
#pragma unroll
            for (int k = 0; k < 9; k++) {
                const float v = iv[k / 3][k % 3];
                acc0 += w[(0 * 64 + c0 + ci) * 9 + k] * v;
                acc1 += w[(1 * 64 + c0 + ci) * 9 + k] * v;
                acc2 += w[(2 * 64 + c0 + ci) * 9 + k] * v;
            }
        }
        __syncthreads();
    }
    const size_t o = (size_t)((n * 3 + 0) * 256 + y) * 256 + t;
    out[o]          = 1.f / (1.f + __expf(-acc0));
    out[o + 65536]  = 1.f / (1.f + __expf(-acc1));
    out[o + 131072] = 1.f / (1.f + __expf(-acc2));
}

// ---------------------------------------------------------------------------
// Workspace (peak 201.5 MB) — same layout as rounds 6-10.
// ---------------------------------------------------------------------------
extern "C" void kernel_launch(void* const* d_in, const int* in_sizes, int n_in,
                              void* d_out, int out_size, void* d_ws, size_t ws_size,
                              hipStream_t stream)
{
    const float* x   = (const float*)d_in[0];
    const float* w1  = (const float*)d_in[1];
    const float* b1  = (const float*)d_in[2];
    const float* w2  = (const float*)d_in[3];
    const float* b2  = (const float*)d_in[4];
    const float* w3  = (const float*)d_in[5];
    const float* b3  = (const float*)d_in[6];
    const float* w4  = (const float*)d_in[7];
    const float* b4  = (const float*)d_in[8];
    const float* cb  = (const float*)d_in[9];
    const float* d1w = (const float*)d_in[10];
    const float* d1b = (const float*)d_in[11];
    const float* d2w = (const float*)d_in[12];
    const float* d2b = (const float*)d_in[13];
    const float* d3w = (const float*)d_in[14];
    const float* d3b = (const float*)d_in[15];
    const float* wo  = (const float*)d_in[16];
    const float* bo  = (const float*)d_in[17];

    char* ws = (char*)d_ws;
    _Float16* H2H = (_Float16*)(ws);
    _Float16* H2L = (_Float16*)(ws + 67108864);
    _Float16* H3H = (_Float16*)(ws + 134217728);
    _Float16* H3L = (_Float16*)(ws + 167772160);
    _Float16* ZH  = (_Float16*)(ws);
    _Float16* ZL  = (_Float16*)(ws + 16777216);
    unsigned short* ZQ = (unsigned short*)(ws + 33554432);
    _Float16* CBH = (_Float16*)(ws + 50331648);
    _Float16* CBL = (_Float16*)(ws + 58720256);
    unsigned short* G1 = (unsigned short*)(ws + 67108864);
    unsigned short* G2 = (unsigned short*)(ws + 134217728);
    unsigned short* G3 = (unsigned short*)(ws);
    unsigned long long* keys = (unsigned long long*)(ws + 201326592);
    float* cn = (float*)(ws + 201326592 + 131072);

    char* oscratch = (char*)d_out;
    _Float16* EW3H = (_Float16*)(oscratch);
    _Float16* EW3L = (_Float16*)(oscratch + 589824);
    _Float16* EW4H = (_Float16*)(oscratch + 1179648);
    _Float16* EW4L = (_Float16*)(oscratch + 3538944);
    unsigned short* WP1 = (unsigned short*)(oscratch + 5898240);
    unsigned short* WP2 = (unsigned short*)(oscratch + 8257536);
    unsigned short* WP3 = (unsigned short*)(oscratch + 8847360);
    _Float16* EW2H = (_Float16*)(oscratch + 8994816);
    _Float16* EW2L = (_Float16*)(oscratch + 9142272);

    float* xrec = (float*)d_out;
    float* idxf = (float*)d_out + (size_t)16 * 3 * 256 * 256;

    // ---- weight prepacks ----
    prepack_conv_kernel<64,  128><<<288,  256, 0, stream>>>(w2, EW2H, EW2L);
    prepack_conv_kernel<128, 256><<<1152, 256, 0, stream>>>(w3, EW3H, EW3L);
    prepack_conv_kernel<256, 512><<<4608, 256, 0, stream>>>(w4, EW4H, EW4L);
    prepack_kernel<512, 256><<<4608, 256, 0, stream>>>(d1w, WP1);
    prepack_kernel<256, 128><<<1152, 256, 0, stream>>>(d2w, WP2);
    prepack_kernel<128, 64 ><<<288,  256, 0, stream>>>(d3w, WP3);

    // ---- encoder ----
    fused_conv12_mfma_kernel<<<dim3(256, 2, 16), 256, 0, stream>>>(x, w1, b1, EW2H, EW2L, b2, H2H, H2L);
    conv_mfma_kernel<128, 256, 128, 128, true ><<<dim3(64, 4, 16), 256, 0, stream>>>(H2H, H2L, EW3H, EW3L, b3, H3H, H3L);
    conv_mfma_kernel<256, 512, 64,  64,  false><<<dim3(16, 8, 16), 256, 0, stream>>>(H3H, H3L, EW4H, EW4L, b4, ZH, ZL);

    // ---- VQ ----
    cnorm_kernel<<<8192, 64, 0, stream>>>(cb, cn);
    init_keys_kernel<<<64, 256, 0, stream>>>(keys);
    split_cb_kernel<<<16384, 256, 0, stream>>>(cb, CBH, CBL);
    vq_mfma_kernel<<<dim3(128, 128), 256, 0, stream>>>(ZH, ZL, CBH, CBL, cn, keys);
    vq_gather_kernel<<<256, 256, 0, stream>>>(keys, cb, ZQ, idxf);

    // ---- decoder (bf16 MFMA) ----
    deconv_mfma_kernel<512, 256, 32,  32,  false><<<dim3(16,  4, 16), 256, 0, stream>>>(ZQ, WP1, d1b, G1);
    deconv_mfma_kernel<256, 128, 64,  64,  false><<<dim3(64,  2, 16), 256, 0, stream>>>(G1, WP2, d2b, G2);
    deconv_mfma_kernel<128, 64,  128, 128, true ><<<dim3(256, 1, 16), 256, 0, stream>>>(G2, WP3, d3b, G3);
    conv_out_kernel<<<dim3(256, 16), 256, 0, stream>>>(G3, wo, bo, xrec);
}